// Round 10
// baseline (181.472 us; speedup 1.0000x reference)
//
#include <hip/hip_runtime.h>
#include <cstdint>
#include <cstddef>

typedef __attribute__((ext_vector_type(8))) __bf16 bf16x8;
typedef __attribute__((ext_vector_type(4))) __bf16 bf16x4;
typedef __attribute__((ext_vector_type(4))) float f32x4;
typedef __attribute__((ext_vector_type(16))) float f32x16;
typedef __attribute__((ext_vector_type(4))) unsigned uint4v;

#define B_ 4
#define T_ 2048
#define C_ 1024
#define H_ 16
#define D_ 64
#define NTILES_ (T_ / 32)
#define TILE_ELEMS_ 2048
#define BH_STRIDE_ ((size_t)NTILES_ * TILE_ELEMS_)  // 131072

__device__ __forceinline__ float fexp2(float x) {
#if __has_builtin(__builtin_amdgcn_exp2f)
  return __builtin_amdgcn_exp2f(x);
#else
  return __expf(x * 0.69314718f);
#endif
}

// ---------------------------------------------------------------- fused cast f32->bf16 (all 5 inputs)
__global__ __launch_bounds__(256) void castall(
    const float* __restrict__ x, const float* __restrict__ wq, const float* __restrict__ wk,
    const float* __restrict__ wv, const float* __restrict__ wp,
    __bf16* __restrict__ xb, __bf16* __restrict__ wqb, __bf16* __restrict__ wkb,
    __bf16* __restrict__ wvb, __bf16* __restrict__ wpb) {
  const int bid = blockIdx.x;
  const float* src;
  __bf16* dst;
  if (bid < 8192)       { src = x  + (size_t)bid * 1024;           dst = xb  + (size_t)bid * 1024; }
  else if (bid < 9216)  { src = wq + (size_t)(bid - 8192) * 1024;  dst = wqb + (size_t)(bid - 8192) * 1024; }
  else if (bid < 10240) { src = wk + (size_t)(bid - 9216) * 1024;  dst = wkb + (size_t)(bid - 9216) * 1024; }
  else if (bid < 11264) { src = wv + (size_t)(bid - 10240) * 1024; dst = wvb + (size_t)(bid - 10240) * 1024; }
  else                  { src = wp + (size_t)(bid - 11264) * 1024; dst = wpb + (size_t)(bid - 11264) * 1024; }
  const int i = threadIdx.x * 4;
  float4 f = *reinterpret_cast<const float4*>(src + i);
  bf16x4 o;
  o[0] = (__bf16)f.x; o[1] = (__bf16)f.y; o[2] = (__bf16)f.z; o[3] = (__bf16)f.w;
  *reinterpret_cast<bf16x4*>(dst + i) = o;
}

// ---------------------------------------------------------------- async global->LDS
__device__ __forceinline__ void gload_lds16(const __bf16* g, __bf16* lds) {
  __builtin_amdgcn_global_load_lds(
      (const __attribute__((address_space(1))) void*)g,
      (__attribute__((address_space(3))) void*)lds, 16, 0, 0);
}

// ---------------------------------------------------------------- proj GEMM (m97 128², proven)
template <typename OUTT, bool BIAS>
__device__ __forceinline__ void gemm_bt_body(const __bf16* __restrict__ A,
                                             const __bf16* __restrict__ Bt,
                                             OUTT* __restrict__ Cp,
                                             const float* __restrict__ bias,
                                             int M, int N, int K) {
  constexpr int BK = 64;
  __shared__ __bf16 As[128 * BK];
  __shared__ __bf16 Bs[128 * BK];
  const int tid = threadIdx.x;
  const int w = tid >> 6, l = tid & 63;
  const int wr = w >> 1, wc = w & 1;
  const int lr = l & 15, lg = l >> 4;
  const int m0 = blockIdx.y * 128, n0 = blockIdx.x * 128;
  const int srow = l >> 3, scol = (l & 7) * 8;

  f32x4 acc[4][4] = {};

  for (int k0 = 0; k0 < K; k0 += BK) {
#pragma unroll
    for (int it = 0; it < 4; ++it) {
      const int c = w * 4 + it;
      gload_lds16(A + (size_t)(m0 + 8 * c + srow) * K + k0 + scol, As + c * 512);
      gload_lds16(Bt + (size_t)(n0 + 8 * c + srow) * K + k0 + scol, Bs + c * 512);
    }
    __syncthreads();
    bf16x8 af[4][2], bfv[4][2];
#pragma unroll
    for (int m = 0; m < 4; ++m)
#pragma unroll
      for (int kk = 0; kk < 2; ++kk)
        af[m][kk] = *reinterpret_cast<const bf16x8*>(As + (wr * 64 + m * 16 + lr) * BK + kk * 32 + lg * 8);
#pragma unroll
    for (int n = 0; n < 4; ++n)
#pragma unroll
      for (int kk = 0; kk < 2; ++kk)
        bfv[n][kk] = *reinterpret_cast<const bf16x8*>(Bs + (wc * 64 + n * 16 + lr) * BK + kk * 32 + lg * 8);
#pragma unroll
    for (int kk = 0; kk < 2; ++kk)
#pragma unroll
      for (int m = 0; m < 4; ++m)
#pragma unroll
        for (int n = 0; n < 4; ++n)
          acc[m][n] = __builtin_amdgcn_mfma_f32_16x16x32_bf16(af[m][kk], bfv[n][kk], acc[m][n], 0, 0, 0);
    __syncthreads();
  }
#pragma unroll
  for (int m = 0; m < 4; ++m)
#pragma unroll
    for (int n = 0; n < 4; ++n) {
      const int col = n0 + wc * 64 + n * 16 + lr;
      float bv = 0.f;
      if (BIAS) bv = bias[col];
#pragma unroll
      for (int j = 0; j < 4; ++j) {
        const int row = m0 + wr * 64 + m * 16 + lg * 4 + j;
        Cp[(size_t)row * N + col] = (OUTT)(acc[m][n][j] + bv);
      }
    }
}

__global__ __launch_bounds__(256) void gemm_proj(const __bf16* __restrict__ ao,
    const __bf16* __restrict__ wp, float* __restrict__ out, const float* __restrict__ bp) {
  gemm_bt_body<float, true>(ao, wp, out, bp, B_ * T_, C_, C_);
}

// ---------------------------------------------------------------- fused QKV GEMM, 256² 8-phase (R9-proven)
// Q outputs pre-scaled by C^-0.5*log2(e) so attn's exp2 needs no multiply.
#define STAGE_A(BUFO, KT, HH)                                                         \
  do {                                                                                \
    const __bf16* s0_ = Agp + (size_t)(m0 + (HH) * 128 + srow) * 1024 + (KT) * 64 + sswz; \
    gload_lds16(s0_, LDSb + (BUFO) + (HH) * 8192 + w * 1024);                         \
    gload_lds16(s0_ + 8 * 1024, LDSb + (BUFO) + (HH) * 8192 + w * 1024 + 512);        \
  } while (0)
#define STAGE_B(BUFO, KT, HH)                                                         \
  do {                                                                                \
    const __bf16* s0_ = Bgp + (size_t)(n0 + (HH) * 128 + srow) * 1024 + (KT) * 64 + sswz; \
    gload_lds16(s0_, LDSb + 32768 + (BUFO) + (HH) * 8192 + w * 1024);                 \
    gload_lds16(s0_ + 8 * 1024, LDSb + 32768 + (BUFO) + (HH) * 8192 + w * 1024 + 512);\
  } while (0)
#define RD_A(M, KK) (*reinterpret_cast<const bf16x8*>(                                \
    LDSb + bufo + (wr * 128 + (M) * 16 + lr) * 64 + (((KK) * 32 + lg * 8) ^ ((lr & 7) * 8))))
#define RD_B(N, KK) (*reinterpret_cast<const bf16x8*>(                                \
    LDSb + 32768 + bufo + (wc * 64 + (N) * 16 + lr) * 64 + (((KK) * 32 + lg * 8) ^ ((lr & 7) * 8))))

__global__ __launch_bounds__(512, 2) void gemm_qkv8(
    const __bf16* __restrict__ Agp, const __bf16* __restrict__ Bgp,
    __bf16* __restrict__ qf, __bf16* __restrict__ kf, __bf16* __restrict__ vf) {
  __shared__ __bf16 LDSb[65536];
  const int tid = threadIdx.x;
  const int w = tid >> 6, l = tid & 63;
  const int wr = w >> 2, wc = w & 3;
  const int lr = l & 15, lg = l >> 4;
  int lin = blockIdx.y * 12 + blockIdx.x;
  lin = (lin & 7) * 48 + (lin >> 3);
  const int bx = lin % 12, by = lin / 12;
  const int m0 = by * 256, n0 = bx * 256;
  const int srow = w * 16 + (l >> 3);
  const int sswz = ((l & 7) ^ ((l >> 3) & 7)) * 8;

  f32x4 acc[8][4] = {};
  bf16x8 afl[4][2], bfl[2][2], bfh[2][2];

  STAGE_A(0, 0, 0); STAGE_A(0, 0, 1);
  STAGE_B(0, 0, 0); STAGE_B(0, 0, 1);
  __builtin_amdgcn_sched_barrier(0);
  asm volatile("s_waitcnt vmcnt(0)" ::: "memory");
  __builtin_amdgcn_s_barrier();
  __builtin_amdgcn_sched_barrier(0);

  for (int t = 0; t < 16; ++t) {
    const int bufo = (t & 1) * 16384;
    const int nbo = ((t + 1) & 1) * 16384;
    const bool st = t < 15;
#pragma unroll
    for (int m = 0; m < 4; ++m) { afl[m][0] = RD_A(m, 0); afl[m][1] = RD_A(m, 1); }
    bfl[0][0] = RD_B(0, 0); bfl[0][1] = RD_B(0, 1);
    bfl[1][0] = RD_B(1, 0); bfl[1][1] = RD_B(1, 1);
    if (st) STAGE_A(nbo, t + 1, 0);
    __builtin_amdgcn_s_setprio(1);
#pragma unroll
    for (int kk = 0; kk < 2; ++kk)
#pragma unroll
      for (int m = 0; m < 4; ++m) {
        acc[m][0] = __builtin_amdgcn_mfma_f32_16x16x32_bf16(afl[m][kk], bfl[0][kk], acc[m][0], 0, 0, 0);
        acc[m][1] = __builtin_amdgcn_mfma_f32_16x16x32_bf16(afl[m][kk], bfl[1][kk], acc[m][1], 0, 0, 0);
      }
    __builtin_amdgcn_s_setprio(0);
    __builtin_amdgcn_s_barrier();
    bfh[0][0] = RD_B(2, 0); bfh[0][1] = RD_B(2, 1);
    bfh[1][0] = RD_B(3, 0); bfh[1][1] = RD_B(3, 1);
    if (st) STAGE_A(nbo, t + 1, 1);
    __builtin_amdgcn_s_setprio(1);
#pragma unroll
    for (int kk = 0; kk < 2; ++kk)
#pragma unroll
      for (int m = 0; m < 4; ++m) {
        acc[m][2] = __builtin_amdgcn_mfma_f32_16x16x32_bf16(afl[m][kk], bfh[0][kk], acc[m][2], 0, 0, 0);
        acc[m][3] = __builtin_amdgcn_mfma_f32_16x16x32_bf16(afl[m][kk], bfh[1][kk], acc[m][3], 0, 0, 0);
      }
    __builtin_amdgcn_s_setprio(0);
    __builtin_amdgcn_s_barrier();
#pragma unroll
    for (int m = 0; m < 4; ++m) { afl[m][0] = RD_A(m + 4, 0); afl[m][1] = RD_A(m + 4, 1); }
    if (st) STAGE_B(nbo, t + 1, 0);
    __builtin_amdgcn_s_setprio(1);
#pragma unroll
    for (int kk = 0; kk < 2; ++kk)
#pragma unroll
      for (int m = 0; m < 4; ++m) {
        acc[m + 4][0] = __builtin_amdgcn_mfma_f32_16x16x32_bf16(afl[m][kk], bfl[0][kk], acc[m + 4][0], 0, 0, 0);
        acc[m + 4][1] = __builtin_amdgcn_mfma_f32_16x16x32_bf16(afl[m][kk], bfl[1][kk], acc[m + 4][1], 0, 0, 0);
      }
    __builtin_amdgcn_s_setprio(0);
    __builtin_amdgcn_s_barrier();
    if (st) STAGE_B(nbo, t + 1, 1);
    __builtin_amdgcn_s_setprio(1);
#pragma unroll
    for (int kk = 0; kk < 2; ++kk)
#pragma unroll
      for (int m = 0; m < 4; ++m) {
        acc[m + 4][2] = __builtin_amdgcn_mfma_f32_16x16x32_bf16(afl[m][kk], bfh[0][kk], acc[m + 4][2], 0, 0, 0);
        acc[m + 4][3] = __builtin_amdgcn_mfma_f32_16x16x32_bf16(afl[m][kk], bfh[1][kk], acc[m + 4][3], 0, 0, 0);
      }
    __builtin_amdgcn_s_setprio(0);
    __builtin_amdgcn_sched_barrier(0);
    asm volatile("s_waitcnt vmcnt(0)" ::: "memory");
    __builtin_amdgcn_s_barrier();
    __builtin_amdgcn_sched_barrier(0);
  }

  // epilogue: LDS re-stage -> fragment order; Q pre-scaled by K2
  __bf16* wl = LDSb + w * 8192;
  const int colb = n0 + wc * 64;
  const int mat = colb >> 10;
  const int h = (colb >> 6) & 15;
  const int b = m0 >> 11;
  const float qsc = (mat == 0) ? 0.04508422f : 1.0f;  // C^-0.5 * log2(e)
#pragma unroll
  for (int m = 0; m < 8; ++m) {
    const int rt = m >> 1;
#pragma unroll
    for (int n = 0; n < 4; ++n) {
      const int d = n * 16 + lr;
#pragma unroll
      for (int j = 0; j < 4; ++j) {
        const int rowloc = (m & 1) * 16 + lg * 4 + j;
        int off;
        if (mat < 2)
          off = ((d >> 4) & 3) * 512 + ((d >> 3) & 1) * 256 + rowloc * 8 + (d & 7);
        else
          off = (d >> 5) * 1024 + ((rowloc >> 4) & 1) * 512 + ((rowloc >> 3) & 1) * 256 +
                (d & 31) * 8 + (rowloc & 7);
        wl[rt * 2048 + off] = (__bf16)(acc[m][n][j] * qsc);
      }
    }
  }
  __bf16* dstbase = (mat == 0 ? qf : mat == 1 ? kf : vf) + (size_t)(b * 16 + h) * BH_STRIDE_;
  const int rt0 = ((m0 + wr * 128) >> 5) & 63;
#pragma unroll
  for (int rt = 0; rt < 4; ++rt)
#pragma unroll
    for (int c = 0; c < 4; ++c) {
      const bf16x8 vchunk = *reinterpret_cast<const bf16x8*>(wl + rt * 2048 + c * 512 + l * 8);
      *reinterpret_cast<bf16x8*>(dstbase + (size_t)(rt0 + rt) * TILE_ELEMS_ + c * 512 + l * 8) = vchunk;
    }
}

// ---------------------------------------------------------------- helpers
__device__ __forceinline__ unsigned pk2(float a, float b) {
  const unsigned short ua = __builtin_bit_cast(unsigned short, (__bf16)a);
  const unsigned short ub = __builtin_bit_cast(unsigned short, (__bf16)b);
  return (unsigned)ua | ((unsigned)ub << 16);
}

// ---------------------------------------------------------------- flash attention v9
// v8 core + kv-range split: 8 waves/block, wave pair (p, hf): hf0 does tiles
// [0,n/2) (unmasked), hf1 does [n/2,n] (owns diagonal). Static-softmax partials
// (acc, l) are additive -> combine via LDS at each phase end; hf0 writes output.
// Q is pre-scaled by K2 in gemm_qkv8, so P = exp2(s) directly.
#define LOADKV(SFX, TT)                                                          \
  do {                                                                           \
    const __bf16* kp_ = kfb + (size_t)(TT) * TILE_ELEMS_ + lx8;                  \
    k##SFX##0 = *reinterpret_cast<const bf16x8*>(kp_);                           \
    k##SFX##1 = *reinterpret_cast<const bf16x8*>(kp_ + 512);                     \
    k##SFX##2 = *reinterpret_cast<const bf16x8*>(kp_ + 1024);                    \
    k##SFX##3 = *reinterpret_cast<const bf16x8*>(kp_ + 1536);                    \
    const __bf16* vp_ = vfb + (size_t)(TT) * TILE_ELEMS_ + lx8;                  \
    v##SFX##0 = *reinterpret_cast<const bf16x8*>(vp_);                           \
    v##SFX##1 = *reinterpret_cast<const bf16x8*>(vp_ + 512);                     \
    v##SFX##2 = *reinterpret_cast<const bf16x8*>(vp_ + 1024);                    \
    v##SFX##3 = *reinterpret_cast<const bf16x8*>(vp_ + 1536);                    \
  } while (0)

#define TILE(SFX, MASKED)                                                        \
  do {                                                                           \
    f32x16 s = {};                                                               \
    __builtin_amdgcn_s_setprio(1);                                               \
    s = __builtin_amdgcn_mfma_f32_32x32x16_bf16(k##SFX##0, qf[0], s, 0, 0, 0);   \
    s = __builtin_amdgcn_mfma_f32_32x32x16_bf16(k##SFX##1, qf[1], s, 0, 0, 0);   \
    s = __builtin_amdgcn_mfma_f32_32x32x16_bf16(k##SFX##2, qf[2], s, 0, 0, 0);   \
    s = __builtin_amdgcn_mfma_f32_32x32x16_bf16(k##SFX##3, qf[3], s, 0, 0, 0);   \
    __builtin_amdgcn_s_setprio(0);                                               \
    float sv[16];                                                                \
    _Pragma("unroll") for (int r = 0; r < 16; ++r) sv[r] = s[r];                 \
    if (MASKED) {                                                                \
      _Pragma("unroll") for (int r = 0; r < 16; ++r) {                           \
        const int kvloc = (r & 3) + 8 * (r >> 2) + 4 * hi;                       \
        sv[r] = (kvloc <= lane31) ? sv[r] : -1e30f;                              \
      }                                                                          \
    }                                                                            \
    _Pragma("unroll") for (int r = 0; r < 16; ++r) sv[r] = fexp2(sv[r]);         \
    unsigned pwv[8];                                                             \
    _Pragma("unroll") for (int ks = 0; ks < 2; ++ks) {                           \
      const unsigned X0 = pk2(sv[ks * 8 + 0], sv[ks * 8 + 1]);                   \
      const unsigned X1 = pk2(sv[ks * 8 + 2], sv[ks * 8 + 3]);                   \
      const unsigned Y0 = pk2(sv[ks * 8 + 4], sv[ks * 8 + 5]);                   \
      const unsigned Y1 = pk2(sv[ks * 8 + 6], sv[ks * 8 + 7]);                   \
      const unsigned sX0 = __shfl_xor(X0, 32);                                   \
      const unsigned sX1 = __shfl_xor(X1, 32);                                   \
      const unsigned sY0 = __shfl_xor(Y0, 32);                                   \
      const unsigned sY1 = __shfl_xor(Y1, 32);                                   \
      pwv[ks * 4 + 0] = hi ? sY0 : X0;                                           \
      pwv[ks * 4 + 1] = hi ? sY1 : X1;                                           \
      pwv[ks * 4 + 2] = hi ? Y0 : sX0;                                           \
      pwv[ks * 4 + 3] = hi ? Y1 : sX1;                                           \
    }                                                                            \
    const uint4v u0 = {pwv[0], pwv[1], pwv[2], pwv[3]};                          \
    const uint4v u1 = {pwv[4], pwv[5], pwv[6], pwv[7]};                          \
    const bf16x8 pf0 = __builtin_bit_cast(bf16x8, u0);                           \
    const bf16x8 pf1 = __builtin_bit_cast(bf16x8, u1);                           \
    __builtin_amdgcn_s_setprio(1);                                               \
    acc0 = __builtin_amdgcn_mfma_f32_32x32x16_bf16(v##SFX##0, pf0, acc0, 0, 0, 0); \
    acc0 = __builtin_amdgcn_mfma_f32_32x32x16_bf16(v##SFX##1, pf1, acc0, 0, 0, 0); \
    acc1 = __builtin_amdgcn_mfma_f32_32x32x16_bf16(v##SFX##2, pf0, acc1, 0, 0, 0); \
    acc1 = __builtin_amdgcn_mfma_f32_32x32x16_bf16(v##SFX##3, pf1, acc1, 0, 0, 0); \
    __builtin_amdgcn_s_setprio(0);                                               \
    float b8[8];                                                                 \
    _Pragma("unroll") for (int r = 0; r < 8; ++r) b8[r] = sv[2 * r] + sv[2 * r + 1]; \
    _Pragma("unroll") for (int r = 0; r < 4; ++r) b8[r] = b8[2 * r] + b8[2 * r + 1]; \
    l_run += (b8[0] + b8[1]) + (b8[2] + b8[3]);                                  \
  } while (0)

__global__ __launch_bounds__(512) void attn_fwd(const __bf16* __restrict__ qfr,
                                                const __bf16* __restrict__ kfr,
                                                const __bf16* __restrict__ vfr,
                                                __bf16* __restrict__ ao) {
  __shared__ float Pls[4 * 64 * 34];  // per-pair partial buffer, stride 34 (2-way free)
  const int tid = threadIdx.x;
  const int w = tid >> 6, l = tid & 63;
  const int p = w >> 1, hf = w & 1;
  const int lane31 = l & 31, hi = l >> 5;
  const int bh = blockIdx.y;
  const int b = bh >> 4;
  const int qx = blockIdx.x * 4 + p;  // 0..31; paired with 63-qx
  const size_t rowbase = (size_t)b * T_;
  const int hoff = (bh & 15) * D_;
  const int lx8 = l * 8;
  const __bf16* qfb = qfr + (size_t)bh * BH_STRIDE_;
  const __bf16* kfb = kfr + (size_t)bh * BH_STRIDE_;
  const __bf16* vfb = vfr + (size_t)bh * BH_STRIDE_;
  float* pb = Pls + p * (64 * 34) + l * 34;

  for (int phase = 0; phase < 2; ++phase) {
    const int qg = (phase ? 63 - qx : qx) * 32;
    const int ntiles = (qg >> 5) + 1;
    const int nh = ntiles >> 1;
    const int tb = hf ? nh : 0;
    const int te = hf ? ntiles : nh;
    const int nt = te - tb;
    const bool dm = (hf == 1);  // diagonal (masked) tile belongs to hf1

    bf16x8 qf[4];
    {
      const __bf16* qp = qfb + (size_t)(qg >> 5) * TILE_ELEMS_ + lx8;
#pragma unroll
      for (int t4 = 0; t4 < 4; ++t4) qf[t4] = *reinterpret_cast<const bf16x8*>(qp + t4 * 512);
    }

    f32x16 acc0 = {};
    f32x16 acc1 = {};
    float l_run = 0.f;

    bf16x8 kA0, kA1, kA2, kA3, vA0, vA1, vA2, vA3;
    bf16x8 kB0, kB1, kB2, kB3, vB0, vB1, vB2, vB3;

    if (nt > 0) {
      LOADKV(A, tb);
      int i = 0;
      for (; i + 1 < nt; ++i) {
        if ((i & 1) == 0) { LOADKV(B, tb + i + 1); TILE(A, false); }
        else              { LOADKV(A, tb + i + 1); TILE(B, false); }
      }
      if ((i & 1) == 0) TILE(A, dm);
      else              TILE(B, dm);
    }

    // combine partials: hf1 -> LDS, hf0 adds + writes output
    if (hf) {
#pragma unroll
      for (int r = 0; r < 16; ++r) { pb[r] = acc0[r]; pb[16 + r] = acc1[r]; }
      pb[32] = l_run;
    }
    __syncthreads();
    if (!hf) {
#pragma unroll
      for (int r = 0; r < 16; ++r) { acc0[r] += pb[r]; acc1[r] += pb[16 + r]; }
      l_run += pb[32];
      l_run += __shfl_xor(l_run, 32);
      const float rl = 1.0f / l_run;
      __bf16* op = ao + (rowbase + qg + lane31) * C_ + hoff + hi * 4;
#pragma unroll
      for (int dblk = 0; dblk < 2; ++dblk)
#pragma unroll
        for (int qd = 0; qd < 4; ++qd) {
          bf16x4 ov;
#pragma unroll
          for (int j = 0; j < 4; ++j) {
            const float av = (dblk == 0) ? acc0[qd * 4 + j] : acc1[qd * 4 + j];
            ov[j] = (__bf16)(av * rl);
          }
          *reinterpret_cast<bf16x4*>(op + dblk * 32 + qd * 8) = ov;
        }
    }
    __syncthreads();  // Pls safe for next phase
  }
}

// ---------------------------------------------------------------- launch
extern "C" void kernel_launch(void* const* d_in, const int* in_sizes, int n_in,
                              void* d_out, int out_size, void* d_ws, size_t ws_size,
                              hipStream_t stream) {
  const float* x  = (const float*)d_in[0];
  const float* Wq = (const float*)d_in[1];
  const float* Wk = (const float*)d_in[2];
  const float* Wv = (const float*)d_in[3];
  const float* Wp = (const float*)d_in[4];
  const float* bp = (const float*)d_in[5];
  float* out = (float*)d_out;

  const int NX = B_ * T_ * C_;
  const int NW = C_ * C_;

  __bf16* xb  = (__bf16*)d_ws;
  __bf16* wqb = xb + NX;     // wq|wk|wv contiguous => fused Bt [3072][1024]
  __bf16* wkb = wqb + NW;
  __bf16* wvb = wkb + NW;
  __bf16* wpb = wvb + NW;
  __bf16* qf  = wpb + NW;    // fragment-order Q (pre-scaled) / K / V
  __bf16* kf  = qf + NX;
  __bf16* vf  = kf + NX;
  __bf16* aob = xb;          // xb dead after gemm_qkv8

  castall<<<12288, 256, 0, stream>>>(x, Wq, Wk, Wv, Wp, xb, wqb, wkb, wvb, wpb);

  gemm_qkv8<<<dim3(12, 32), 512, 0, stream>>>(xb, wqb, qf, kf, vf);
  attn_fwd<<<dim3(8, B_ * H_), 512, 0, stream>>>(qf, kf, vf, aob);
  gemm_proj<<<dim3(C_ / 128, (B_ * T_) / 128), 256, 0, stream>>>(aob, wpb, out, bp);
}

// Round 11
// 172.010 us; speedup vs baseline: 1.0550x; 1.0550x over previous
//
#include <hip/hip_runtime.h>
#include <cstdint>
#include <cstddef>

typedef __attribute__((ext_vector_type(8))) __bf16 bf16x8;
typedef __attribute__((ext_vector_type(4))) __bf16 bf16x4;
typedef __attribute__((ext_vector_type(4))) float f32x4;
typedef __attribute__((ext_vector_type(16))) float f32x16;
typedef __attribute__((ext_vector_type(4))) unsigned uint4v;

#define B_ 4
#define T_ 2048
#define C_ 1024
#define H_ 16
#define D_ 64
#define NTILES_ (T_ / 32)
#define TILE_ELEMS_ 2048
#define BH_STRIDE_ ((size_t)NTILES_ * TILE_ELEMS_)  // 131072

__device__ __forceinline__ float fexp2(float x) {
#if __has_builtin(__builtin_amdgcn_exp2f)
  return __builtin_amdgcn_exp2f(x);
#else
  return __expf(x * 0.69314718f);
#endif
}

// ---------------------------------------------------------------- fused cast f32->bf16
__global__ __launch_bounds__(256) void castall(
    const float* __restrict__ x, const float* __restrict__ wq, const float* __restrict__ wk,
    const float* __restrict__ wv, const float* __restrict__ wp,
    __bf16* __restrict__ xb, __bf16* __restrict__ wqb, __bf16* __restrict__ wkb,
    __bf16* __restrict__ wvb, __bf16* __restrict__ wpb) {
  const int bid = blockIdx.x;
  const float* src;
  __bf16* dst;
  if (bid < 8192)       { src = x  + (size_t)bid * 1024;           dst = xb  + (size_t)bid * 1024; }
  else if (bid < 9216)  { src = wq + (size_t)(bid - 8192) * 1024;  dst = wqb + (size_t)(bid - 8192) * 1024; }
  else if (bid < 10240) { src = wk + (size_t)(bid - 9216) * 1024;  dst = wkb + (size_t)(bid - 9216) * 1024; }
  else if (bid < 11264) { src = wv + (size_t)(bid - 10240) * 1024; dst = wvb + (size_t)(bid - 10240) * 1024; }
  else                  { src = wp + (size_t)(bid - 11264) * 1024; dst = wpb + (size_t)(bid - 11264) * 1024; }
  const int i = threadIdx.x * 4;
  float4 f = *reinterpret_cast<const float4*>(src + i);
  bf16x4 o;
  o[0] = (__bf16)f.x; o[1] = (__bf16)f.y; o[2] = (__bf16)f.z; o[3] = (__bf16)f.w;
  *reinterpret_cast<bf16x4*>(dst + i) = o;
}

// ---------------------------------------------------------------- async global->LDS
__device__ __forceinline__ void gload_lds16(const __bf16* g, __bf16* lds) {
  __builtin_amdgcn_global_load_lds(
      (const __attribute__((address_space(1))) void*)g,
      (__attribute__((address_space(3))) void*)lds, 16, 0, 0);
}

// ---------------------------------------------------------------- 256² 8-phase staging/read macros
#define STAGE_A(BUFO, KT, HH)                                                         \
  do {                                                                                \
    const __bf16* s0_ = Agp + (size_t)(m0 + (HH) * 128 + srow) * 1024 + (KT) * 64 + sswz; \
    gload_lds16(s0_, LDSb + (BUFO) + (HH) * 8192 + w * 1024);                         \
    gload_lds16(s0_ + 8 * 1024, LDSb + (BUFO) + (HH) * 8192 + w * 1024 + 512);        \
  } while (0)
#define STAGE_B(BUFO, KT, HH)                                                         \
  do {                                                                                \
    const __bf16* s0_ = Bgp + (size_t)(n0 + (HH) * 128 + srow) * 1024 + (KT) * 64 + sswz; \
    gload_lds16(s0_, LDSb + 32768 + (BUFO) + (HH) * 8192 + w * 1024);                 \
    gload_lds16(s0_ + 8 * 1024, LDSb + 32768 + (BUFO) + (HH) * 8192 + w * 1024 + 512);\
  } while (0)
#define RD_A(M, KK) (*reinterpret_cast<const bf16x8*>(                                \
    LDSb + bufo + (wr * 128 + (M) * 16 + lr) * 64 + (((KK) * 32 + lg * 8) ^ ((lr & 7) * 8))))
#define RD_B(N, KK) (*reinterpret_cast<const bf16x8*>(                                \
    LDSb + 32768 + bufo + (wc * 64 + (N) * 16 + lr) * 64 + (((KK) * 32 + lg * 8) ^ ((lr & 7) * 8))))

// K-loop body shared by both 8-phase GEMMs (16 K-tiles of 64)
#define GEMM8_KLOOP                                                                   \
  STAGE_A(0, 0, 0); STAGE_A(0, 0, 1);                                                 \
  STAGE_B(0, 0, 0); STAGE_B(0, 0, 1);                                                 \
  __builtin_amdgcn_sched_barrier(0);                                                  \
  asm volatile("s_waitcnt vmcnt(0)" ::: "memory");                                    \
  __builtin_amdgcn_s_barrier();                                                       \
  __builtin_amdgcn_sched_barrier(0);                                                  \
  for (int t = 0; t < 16; ++t) {                                                      \
    const int bufo = (t & 1) * 16384;                                                 \
    const int nbo = ((t + 1) & 1) * 16384;                                            \
    const bool st = t < 15;                                                           \
    _Pragma("unroll")                                                                 \
    for (int m = 0; m < 4; ++m) { afl[m][0] = RD_A(m, 0); afl[m][1] = RD_A(m, 1); }   \
    bfl[0][0] = RD_B(0, 0); bfl[0][1] = RD_B(0, 1);                                   \
    bfl[1][0] = RD_B(1, 0); bfl[1][1] = RD_B(1, 1);                                   \
    if (st) STAGE_A(nbo, t + 1, 0);                                                   \
    __builtin_amdgcn_s_setprio(1);                                                    \
    _Pragma("unroll")                                                                 \
    for (int kk = 0; kk < 2; ++kk)                                                    \
      _Pragma("unroll")                                                               \
      for (int m = 0; m < 4; ++m) {                                                   \
        acc[m][0] = __builtin_amdgcn_mfma_f32_16x16x32_bf16(afl[m][kk], bfl[0][kk], acc[m][0], 0, 0, 0); \
        acc[m][1] = __builtin_amdgcn_mfma_f32_16x16x32_bf16(afl[m][kk], bfl[1][kk], acc[m][1], 0, 0, 0); \
      }                                                                               \
    __builtin_amdgcn_s_setprio(0);                                                    \
    __builtin_amdgcn_s_barrier();                                                     \
    bfh[0][0] = RD_B(2, 0); bfh[0][1] = RD_B(2, 1);                                   \
    bfh[1][0] = RD_B(3, 0); bfh[1][1] = RD_B(3, 1);                                   \
    if (st) STAGE_A(nbo, t + 1, 1);                                                   \
    __builtin_amdgcn_s_setprio(1);                                                    \
    _Pragma("unroll")                                                                 \
    for (int kk = 0; kk < 2; ++kk)                                                    \
      _Pragma("unroll")                                                               \
      for (int m = 0; m < 4; ++m) {                                                   \
        acc[m][2] = __builtin_amdgcn_mfma_f32_16x16x32_bf16(afl[m][kk], bfh[0][kk], acc[m][2], 0, 0, 0); \
        acc[m][3] = __builtin_amdgcn_mfma_f32_16x16x32_bf16(afl[m][kk], bfh[1][kk], acc[m][3], 0, 0, 0); \
      }                                                                               \
    __builtin_amdgcn_s_setprio(0);                                                    \
    __builtin_amdgcn_s_barrier();                                                     \
    _Pragma("unroll")                                                                 \
    for (int m = 0; m < 4; ++m) { afl[m][0] = RD_A(m + 4, 0); afl[m][1] = RD_A(m + 4, 1); } \
    if (st) STAGE_B(nbo, t + 1, 0);                                                   \
    __builtin_amdgcn_s_setprio(1);                                                    \
    _Pragma("unroll")                                                                 \
    for (int kk = 0; kk < 2; ++kk)                                                    \
      _Pragma("unroll")                                                               \
      for (int m = 0; m < 4; ++m) {                                                   \
        acc[m + 4][0] = __builtin_amdgcn_mfma_f32_16x16x32_bf16(afl[m][kk], bfl[0][kk], acc[m + 4][0], 0, 0, 0); \
        acc[m + 4][1] = __builtin_amdgcn_mfma_f32_16x16x32_bf16(afl[m][kk], bfl[1][kk], acc[m + 4][1], 0, 0, 0); \
      }                                                                               \
    __builtin_amdgcn_s_setprio(0);                                                    \
    __builtin_amdgcn_s_barrier();                                                     \
    if (st) STAGE_B(nbo, t + 1, 1);                                                   \
    __builtin_amdgcn_s_setprio(1);                                                    \
    _Pragma("unroll")                                                                 \
    for (int kk = 0; kk < 2; ++kk)                                                    \
      _Pragma("unroll")                                                               \
      for (int m = 0; m < 4; ++m) {                                                   \
        acc[m + 4][2] = __builtin_amdgcn_mfma_f32_16x16x32_bf16(afl[m][kk], bfh[0][kk], acc[m + 4][2], 0, 0, 0); \
        acc[m + 4][3] = __builtin_amdgcn_mfma_f32_16x16x32_bf16(afl[m][kk], bfh[1][kk], acc[m + 4][3], 0, 0, 0); \
      }                                                                               \
    __builtin_amdgcn_s_setprio(0);                                                    \
    __builtin_amdgcn_sched_barrier(0);                                                \
    asm volatile("s_waitcnt vmcnt(0)" ::: "memory");                                  \
    __builtin_amdgcn_s_barrier();                                                     \
    __builtin_amdgcn_sched_barrier(0);                                                \
  }

// ---------------------------------------------------------------- fused QKV GEMM (R9-proven)
__global__ __launch_bounds__(512, 2) void gemm_qkv8(
    const __bf16* __restrict__ Agp, const __bf16* __restrict__ Bgp,
    __bf16* __restrict__ qf, __bf16* __restrict__ kf, __bf16* __restrict__ vf) {
  __shared__ __bf16 LDSb[65536];
  const int tid = threadIdx.x;
  const int w = tid >> 6, l = tid & 63;
  const int wr = w >> 2, wc = w & 3;
  const int lr = l & 15, lg = l >> 4;
  int lin = blockIdx.y * 12 + blockIdx.x;
  lin = (lin & 7) * 48 + (lin >> 3);
  const int bx = lin % 12, by = lin / 12;
  const int m0 = by * 256, n0 = bx * 256;
  const int srow = w * 16 + (l >> 3);
  const int sswz = ((l & 7) ^ ((l >> 3) & 7)) * 8;

  f32x4 acc[8][4] = {};
  bf16x8 afl[4][2], bfl[2][2], bfh[2][2];

  GEMM8_KLOOP

  // epilogue: LDS re-stage -> fragment order; Q pre-scaled by K2
  __bf16* wl = LDSb + w * 8192;
  const int colb = n0 + wc * 64;
  const int mat = colb >> 10;
  const int h = (colb >> 6) & 15;
  const int b = m0 >> 11;
  const float qsc = (mat == 0) ? 0.04508422f : 1.0f;  // C^-0.5 * log2(e)
#pragma unroll
  for (int m = 0; m < 8; ++m) {
    const int rt = m >> 1;
#pragma unroll
    for (int n = 0; n < 4; ++n) {
      const int d = n * 16 + lr;
#pragma unroll
      for (int j = 0; j < 4; ++j) {
        const int rowloc = (m & 1) * 16 + lg * 4 + j;
        int off;
        if (mat < 2)
          off = ((d >> 4) & 3) * 512 + ((d >> 3) & 1) * 256 + rowloc * 8 + (d & 7);
        else
          off = (d >> 5) * 1024 + ((rowloc >> 4) & 1) * 512 + ((rowloc >> 3) & 1) * 256 +
                (d & 31) * 8 + (rowloc & 7);
        wl[rt * 2048 + off] = (__bf16)(acc[m][n][j] * qsc);
      }
    }
  }
  __bf16* dstbase = (mat == 0 ? qf : mat == 1 ? kf : vf) + (size_t)(b * 16 + h) * BH_STRIDE_;
  const int rt0 = ((m0 + wr * 128) >> 5) & 63;
#pragma unroll
  for (int rt = 0; rt < 4; ++rt)
#pragma unroll
    for (int c = 0; c < 4; ++c) {
      const bf16x8 vchunk = *reinterpret_cast<const bf16x8*>(wl + rt * 2048 + c * 512 + l * 8);
      *reinterpret_cast<bf16x8*>(dstbase + (size_t)(rt0 + rt) * TILE_ELEMS_ + c * 512 + l * 8) = vchunk;
    }
}

// ---------------------------------------------------------------- proj GEMM, 8-phase 256²
// out[8192][1024] f32 = ao[8192][1024] x wp[1024][1024]^T + bias
__global__ __launch_bounds__(512, 2) void gemm_proj8(
    const __bf16* __restrict__ Agp, const __bf16* __restrict__ Bgp,
    float* __restrict__ out, const float* __restrict__ bias) {
  __shared__ __bf16 LDSb[65536];
  const int tid = threadIdx.x;
  const int w = tid >> 6, l = tid & 63;
  const int wr = w >> 2, wc = w & 3;
  const int lr = l & 15, lg = l >> 4;
  int lin = blockIdx.y * 4 + blockIdx.x;           // 128 blocks; 128%8==0
  lin = (lin & 7) * 16 + (lin >> 3);
  const int bx = lin & 3, by = lin >> 2;
  const int m0 = by * 256, n0 = bx * 256;
  const int srow = w * 16 + (l >> 3);
  const int sswz = ((l & 7) ^ ((l >> 3) & 7)) * 8;

  f32x4 acc[8][4] = {};
  bf16x8 afl[4][2], bfl[2][2], bfh[2][2];

  GEMM8_KLOOP

  // epilogue: direct f32 + bias store
  const int colb = n0 + wc * 64;
#pragma unroll
  for (int m = 0; m < 8; ++m) {
    const int row = m0 + wr * 128 + (m >> 1) * 32 + (m & 1) * 16 + lg * 4;
#pragma unroll
    for (int n = 0; n < 4; ++n) {
      const int col = colb + n * 16 + lr;
      const float bv = bias[col];
#pragma unroll
      for (int j = 0; j < 4; ++j)
        out[(size_t)(row + j) * 1024 + col] = acc[m][n][j] + bv;
    }
  }
}

// ---------------------------------------------------------------- helpers
__device__ __forceinline__ unsigned pk2(float a, float b) {
  const unsigned short ua = __builtin_bit_cast(unsigned short, (__bf16)a);
  const unsigned short ub = __builtin_bit_cast(unsigned short, (__bf16)b);
  return (unsigned)ua | ((unsigned)ub << 16);
}

// ---------------------------------------------------------------- flash attention v10
// = v9 + bh->XCD affinity: 1-D grid, bh = lin&63 => lin%8 = bh%8 so all 8 blocks
// of a (b,h) share one XCD; per-XCD K/V working set = 8 heads x 0.5MB = 4MB (L2-fit).
#define LOADKV(SFX, TT)                                                          \
  do {                                                                           \
    const __bf16* kp_ = kfb + (size_t)(TT) * TILE_ELEMS_ + lx8;                  \
    k##SFX##0 = *reinterpret_cast<const bf16x8*>(kp_);                           \
    k##SFX##1 = *reinterpret_cast<const bf16x8*>(kp_ + 512);                     \
    k##SFX##2 = *reinterpret_cast<const bf16x8*>(kp_ + 1024);                    \
    k##SFX##3 = *reinterpret_cast<const bf16x8*>(kp_ + 1536);                    \
    const __bf16* vp_ = vfb + (size_t)(TT) * TILE_ELEMS_ + lx8;                  \
    v##SFX##0 = *reinterpret_cast<const bf16x8*>(vp_);                           \
    v##SFX##1 = *reinterpret_cast<const bf16x8*>(vp_ + 512);                     \
    v##SFX##2 = *reinterpret_cast<const bf16x8*>(vp_ + 1024);                    \
    v##SFX##3 = *reinterpret_cast<const bf16x8*>(vp_ + 1536);                    \
  } while (0)

#define TILE(SFX, MASKED)                                                        \
  do {                                                                           \
    f32x16 s = {};                                                               \
    __builtin_amdgcn_s_setprio(1);                                               \
    s = __builtin_amdgcn_mfma_f32_32x32x16_bf16(k##SFX##0, qf[0], s, 0, 0, 0);   \
    s = __builtin_amdgcn_mfma_f32_32x32x16_bf16(k##SFX##1, qf[1], s, 0, 0, 0);   \
    s = __builtin_amdgcn_mfma_f32_32x32x16_bf16(k##SFX##2, qf[2], s, 0, 0, 0);   \
    s = __builtin_amdgcn_mfma_f32_32x32x16_bf16(k##SFX##3, qf[3], s, 0, 0, 0);   \
    __builtin_amdgcn_s_setprio(0);                                               \
    float sv[16];                                                                \
    _Pragma("unroll") for (int r = 0; r < 16; ++r) sv[r] = s[r];                 \
    if (MASKED) {                                                                \
      _Pragma("unroll") for (int r = 0; r < 16; ++r) {                           \
        const int kvloc = (r & 3) + 8 * (r >> 2) + 4 * hi;                       \
        sv[r] = (kvloc <= lane31) ? sv[r] : -1e30f;                              \
      }                                                                          \
    }                                                                            \
    _Pragma("unroll") for (int r = 0; r < 16; ++r) sv[r] = fexp2(sv[r]);         \
    unsigned pwv[8];                                                             \
    _Pragma("unroll") for (int ks = 0; ks < 2; ++ks) {                           \
      const unsigned X0 = pk2(sv[ks * 8 + 0], sv[ks * 8 + 1]);                   \
      const unsigned X1 = pk2(sv[ks * 8 + 2], sv[ks * 8 + 3]);                   \
      const unsigned Y0 = pk2(sv[ks * 8 + 4], sv[ks * 8 + 5]);                   \
      const unsigned Y1 = pk2(sv[ks * 8 + 6], sv[ks * 8 + 7]);                   \
      const unsigned sX0 = __shfl_xor(X0, 32);                                   \
      const unsigned sX1 = __shfl_xor(X1, 32);                                   \
      const unsigned sY0 = __shfl_xor(Y0, 32);                                   \
      const unsigned sY1 = __shfl_xor(Y1, 32);                                   \
      pwv[ks * 4 + 0] = hi ? sY0 : X0;                                           \
      pwv[ks * 4 + 1] = hi ? sY1 : X1;                                           \
      pwv[ks * 4 + 2] = hi ? Y0 : sX0;                                           \
      pwv[ks * 4 + 3] = hi ? Y1 : sX1;                                           \
    }                                                                            \
    const uint4v u0 = {pwv[0], pwv[1], pwv[2], pwv[3]};                          \
    const uint4v u1 = {pwv[4], pwv[5], pwv[6], pwv[7]};                          \
    const bf16x8 pf0 = __builtin_bit_cast(bf16x8, u0);                           \
    const bf16x8 pf1 = __builtin_bit_cast(bf16x8, u1);                           \
    __builtin_amdgcn_s_setprio(1);                                               \
    acc0 = __builtin_amdgcn_mfma_f32_32x32x16_bf16(v##SFX##0, pf0, acc0, 0, 0, 0); \
    acc0 = __builtin_amdgcn_mfma_f32_32x32x16_bf16(v##SFX##1, pf1, acc0, 0, 0, 0); \
    acc1 = __builtin_amdgcn_mfma_f32_32x32x16_bf16(v##SFX##2, pf0, acc1, 0, 0, 0); \
    acc1 = __builtin_amdgcn_mfma_f32_32x32x16_bf16(v##SFX##3, pf1, acc1, 0, 0, 0); \
    __builtin_amdgcn_s_setprio(0);                                               \
    float b8[8];                                                                 \
    _Pragma("unroll") for (int r = 0; r < 8; ++r) b8[r] = sv[2 * r] + sv[2 * r + 1]; \
    _Pragma("unroll") for (int r = 0; r < 4; ++r) b8[r] = b8[2 * r] + b8[2 * r + 1]; \
    l_run += (b8[0] + b8[1]) + (b8[2] + b8[3]);                                  \
  } while (0)

__global__ __launch_bounds__(512) void attn_fwd(const __bf16* __restrict__ qfr,
                                                const __bf16* __restrict__ kfr,
                                                const __bf16* __restrict__ vfr,
                                                __bf16* __restrict__ ao) {
  __shared__ float Pls[4 * 64 * 34];
  const int tid = threadIdx.x;
  const int w = tid >> 6, l = tid & 63;
  const int p = w >> 1, hf = w & 1;
  const int lane31 = l & 31, hi = l >> 5;
  const int bh = blockIdx.x & 63;   // XCD affinity: lin%8 == bh%8
  const int qi = blockIdx.x >> 6;   // 0..7
  const int b = bh >> 4;
  const int qx = qi * 4 + p;        // 0..31; paired with 63-qx
  const size_t rowbase = (size_t)b * T_;
  const int hoff = (bh & 15) * D_;
  const int lx8 = l * 8;
  const __bf16* qfb = qfr + (size_t)bh * BH_STRIDE_;
  const __bf16* kfb = kfr + (size_t)bh * BH_STRIDE_;
  const __bf16* vfb = vfr + (size_t)bh * BH_STRIDE_;
  float* pb = Pls + p * (64 * 34) + l * 34;

  for (int phase = 0; phase < 2; ++phase) {
    const int qg = (phase ? 63 - qx : qx) * 32;
    const int ntiles = (qg >> 5) + 1;
    const int nh = ntiles >> 1;
    const int tb = hf ? nh : 0;
    const int te = hf ? ntiles : nh;
    const int nt = te - tb;
    const bool dm = (hf == 1);

    bf16x8 qf[4];
    {
      const __bf16* qp = qfb + (size_t)(qg >> 5) * TILE_ELEMS_ + lx8;
#pragma unroll
      for (int t4 = 0; t4 < 4; ++t4) qf[t4] = *reinterpret_cast<const bf16x8*>(qp + t4 * 512);
    }

    f32x16 acc0 = {};
    f32x16 acc1 = {};
    float l_run = 0.f;

    bf16x8 kA0, kA1, kA2, kA3, vA0, vA1, vA2, vA3;
    bf16x8 kB0, kB1, kB2, kB3, vB0, vB1, vB2, vB3;

    if (nt > 0) {
      LOADKV(A, tb);
      int i = 0;
      for (; i + 1 < nt; ++i) {
        if ((i & 1) == 0) { LOADKV(B, tb + i + 1); TILE(A, false); }
        else              { LOADKV(A, tb + i + 1); TILE(B, false); }
      }
      if ((i & 1) == 0) TILE(A, dm);
      else              TILE(B, dm);
    }

    if (hf) {
#pragma unroll
      for (int r = 0; r < 16; ++r) { pb[r] = acc0[r]; pb[16 + r] = acc1[r]; }
      pb[32] = l_run;
    }
    __syncthreads();
    if (!hf) {
#pragma unroll
      for (int r = 0; r < 16; ++r) { acc0[r] += pb[r]; acc1[r] += pb[16 + r]; }
      l_run += pb[32];
      l_run += __shfl_xor(l_run, 32);
      const float rl = 1.0f / l_run;
      __bf16* op = ao + (rowbase + qg + lane31) * C_ + hoff + hi * 4;
#pragma unroll
      for (int dblk = 0; dblk < 2; ++dblk)
#pragma unroll
        for (int qd = 0; qd < 4; ++qd) {
          bf16x4 ov;
#pragma unroll
          for (int j = 0; j < 4; ++j) {
            const float av = (dblk == 0) ? acc0[qd * 4 + j] : acc1[qd * 4 + j];
            ov[j] = (__bf16)(av * rl);
          }
          *reinterpret_cast<bf16x4*>(op + dblk * 32 + qd * 8) = ov;
        }
    }
    __syncthreads();
  }
}

// ---------------------------------------------------------------- launch
extern "C" void kernel_launch(void* const* d_in, const int* in_sizes, int n_in,
                              void* d_out, int out_size, void* d_ws, size_t ws_size,
                              hipStream_t stream) {
  const float* x  = (const float*)d_in[0];
  const float* Wq = (const float*)d_in[1];
  const float* Wk = (const float*)d_in[2];
  const float* Wv = (const float*)d_in[3];
  const float* Wp = (const float*)d_in[4];
  const float* bp = (const float*)d_in[5];
  float* out = (float*)d_out;

  const int NX = B_ * T_ * C_;
  const int NW = C_ * C_;

  __bf16* xb  = (__bf16*)d_ws;
  __bf16* wqb = xb + NX;
  __bf16* wkb = wqb + NW;
  __bf16* wvb = wkb + NW;
  __bf16* wpb = wvb + NW;
  __bf16* qf  = wpb + NW;
  __bf16* kf  = qf + NX;
  __bf16* vf  = kf + NX;
  __bf16* aob = xb;  // xb dead after gemm_qkv8

  castall<<<12288, 256, 0, stream>>>(x, Wq, Wk, Wv, Wp, xb, wqb, wkb, wvb, wpb);

  gemm_qkv8<<<dim3(12, 32), 512, 0, stream>>>(xb, wqb, qf, kf, vf);
  attn_fwd<<<512, 512, 0, stream>>>(qf, kf, vf, aob);
  gemm_proj8<<<dim3(4, 32), 512, 0, stream>>>(aob, wpb, out, bp);
}

// Round 12
// 160.721 us; speedup vs baseline: 1.1291x; 1.0702x over previous
//
#include <hip/hip_runtime.h>
#include <cstdint>
#include <cstddef>

typedef __attribute__((ext_vector_type(8))) __bf16 bf16x8;
typedef __attribute__((ext_vector_type(4))) __bf16 bf16x4;
typedef __attribute__((ext_vector_type(4))) float f32x4;
typedef __attribute__((ext_vector_type(16))) float f32x16;
typedef __attribute__((ext_vector_type(4))) unsigned uint4v;

#define B_ 4
#define T_ 2048
#define C_ 1024
#define H_ 16
#define D_ 64
#define NTILES_ (T_ / 32)
#define TILE_ELEMS_ 2048
#define BH_STRIDE_ ((size_t)NTILES_ * TILE_ELEMS_)  // 131072

__device__ __forceinline__ float fexp2(float x) {
#if __has_builtin(__builtin_amdgcn_exp2f)
  return __builtin_amdgcn_exp2f(x);
#else
  return __expf(x * 0.69314718f);
#endif
}

// ---------------------------------------------------------------- fused cast f32->bf16
__global__ __launch_bounds__(256) void castall(
    const float* __restrict__ x, const float* __restrict__ wq, const float* __restrict__ wk,
    const float* __restrict__ wv, const float* __restrict__ wp,
    __bf16* __restrict__ xb, __bf16* __restrict__ wqb, __bf16* __restrict__ wkb,
    __bf16* __restrict__ wvb, __bf16* __restrict__ wpb) {
  const int bid = blockIdx.x;
  const float* src;
  __bf16* dst;
  if (bid < 8192)       { src = x  + (size_t)bid * 1024;           dst = xb  + (size_t)bid * 1024; }
  else if (bid < 9216)  { src = wq + (size_t)(bid - 8192) * 1024;  dst = wqb + (size_t)(bid - 8192) * 1024; }
  else if (bid < 10240) { src = wk + (size_t)(bid - 9216) * 1024;  dst = wkb + (size_t)(bid - 9216) * 1024; }
  else if (bid < 11264) { src = wv + (size_t)(bid - 10240) * 1024; dst = wvb + (size_t)(bid - 10240) * 1024; }
  else                  { src = wp + (size_t)(bid - 11264) * 1024; dst = wpb + (size_t)(bid - 11264) * 1024; }
  const int i = threadIdx.x * 4;
  float4 f = *reinterpret_cast<const float4*>(src + i);
  bf16x4 o;
  o[0] = (__bf16)f.x; o[1] = (__bf16)f.y; o[2] = (__bf16)f.z; o[3] = (__bf16)f.w;
  *reinterpret_cast<bf16x4*>(dst + i) = o;
}

// ---------------------------------------------------------------- async global->LDS
__device__ __forceinline__ void gload_lds16(const __bf16* g, __bf16* lds) {
  __builtin_amdgcn_global_load_lds(
      (const __attribute__((address_space(1))) void*)g,
      (__attribute__((address_space(3))) void*)lds, 16, 0, 0);
}

// ---------------------------------------------------------------- 8-phase GEMM, BM=256 x BN=128
// 8 waves = 4M x 2N, per-wave 64x64 output, acc[4][4]. BK=64, 16 K-tiles.
// LDS: A [2][256][64] @0 (32768 elems), B [2][128][64] @32768 (16384 elems) = 96KB.
// T2 swizzle: source chunk pre-swizzled, reads XOR (lr&7)*8.
#define ST_A41(BUFO, KT, HH)                                                          \
  do {                                                                                \
    const __bf16* s0_ = Agp + (size_t)(m0 + (HH) * 128 + srow) * 1024 + (KT) * 64 + sswz; \
    gload_lds16(s0_, LDSb + (BUFO) + (HH) * 8192 + w * 1024);                         \
    gload_lds16(s0_ + 8 * 1024, LDSb + (BUFO) + (HH) * 8192 + w * 1024 + 512);        \
  } while (0)
#define ST_B41(BUFO, KT)                                                              \
  do {                                                                                \
    const __bf16* s0_ = Bgp + (size_t)(n0 + srow) * 1024 + (KT) * 64 + sswz;          \
    gload_lds16(s0_, LDSb + 32768 + (BUFO) + w * 1024);                               \
    gload_lds16(s0_ + 8 * 1024, LDSb + 32768 + (BUFO) + w * 1024 + 512);              \
  } while (0)
#define RDA41(M, KK) (*reinterpret_cast<const bf16x8*>(                               \
    LDSb + bufoA + (wr * 64 + (M) * 16 + lr) * 64 + (((KK) * 32 + lg * 8) ^ ((lr & 7) * 8))))
#define RDB41(N, KK) (*reinterpret_cast<const bf16x8*>(                               \
    LDSb + 32768 + bufoB + (wc * 64 + (N) * 16 + lr) * 64 + (((KK) * 32 + lg * 8) ^ ((lr & 7) * 8))))

#define GEMM8_KLOOP_41                                                                \
  ST_A41(0, 0, 0); ST_A41(0, 0, 1); ST_B41(0, 0);                                     \
  __builtin_amdgcn_sched_barrier(0);                                                  \
  asm volatile("s_waitcnt vmcnt(0)" ::: "memory");                                    \
  __builtin_amdgcn_s_barrier();                                                       \
  __builtin_amdgcn_sched_barrier(0);                                                  \
  for (int t = 0; t < 16; ++t) {                                                      \
    const int bufoA = (t & 1) * 16384;                                                \
    const int bufoB = (t & 1) * 8192;                                                 \
    const int nboA = ((t + 1) & 1) * 16384;                                           \
    const int nboB = ((t + 1) & 1) * 8192;                                            \
    const bool st = t < 15;                                                           \
    /* P0: A m0-1 + B n0-1 ; stage A(t+1) half0 ; MFMA m01 x n01 */                   \
    afA[0][0] = RDA41(0, 0); afA[0][1] = RDA41(0, 1);                                 \
    afA[1][0] = RDA41(1, 0); afA[1][1] = RDA41(1, 1);                                 \
    bfA[0][0] = RDB41(0, 0); bfA[0][1] = RDB41(0, 1);                                 \
    bfA[1][0] = RDB41(1, 0); bfA[1][1] = RDB41(1, 1);                                 \
    if (st) ST_A41(nboA, t + 1, 0);                                                   \
    __builtin_amdgcn_s_setprio(1);                                                    \
    _Pragma("unroll")                                                                 \
    for (int kk = 0; kk < 2; ++kk)                                                    \
      _Pragma("unroll")                                                               \
      for (int m = 0; m < 2; ++m) {                                                   \
        acc[m][0] = __builtin_amdgcn_mfma_f32_16x16x32_bf16(afA[m][kk], bfA[0][kk], acc[m][0], 0, 0, 0); \
        acc[m][1] = __builtin_amdgcn_mfma_f32_16x16x32_bf16(afA[m][kk], bfA[1][kk], acc[m][1], 0, 0, 0); \
      }                                                                               \
    __builtin_amdgcn_s_setprio(0);                                                    \
    __builtin_amdgcn_s_barrier();                                                     \
    /* P1: B n2-3 ; stage A(t+1) half1 ; MFMA m01 x n23 */                            \
    bfB[0][0] = RDB41(2, 0); bfB[0][1] = RDB41(2, 1);                                 \
    bfB[1][0] = RDB41(3, 0); bfB[1][1] = RDB41(3, 1);                                 \
    if (st) ST_A41(nboA, t + 1, 1);                                                   \
    __builtin_amdgcn_s_setprio(1);                                                    \
    _Pragma("unroll")                                                                 \
    for (int kk = 0; kk < 2; ++kk)                                                    \
      _Pragma("unroll")                                                               \
      for (int m = 0; m < 2; ++m) {                                                   \
        acc[m][2] = __builtin_amdgcn_mfma_f32_16x16x32_bf16(afA[m][kk], bfB[0][kk], acc[m][2], 0, 0, 0); \
        acc[m][3] = __builtin_amdgcn_mfma_f32_16x16x32_bf16(afA[m][kk], bfB[1][kk], acc[m][3], 0, 0, 0); \
      }                                                                               \
    __builtin_amdgcn_s_setprio(0);                                                    \
    __builtin_amdgcn_s_barrier();                                                     \
    /* P2: A m2-3 ; stage B(t+1) ; MFMA m23 x n01 */                                  \
    afB[0][0] = RDA41(2, 0); afB[0][1] = RDA41(2, 1);                                 \
    afB[1][0] = RDA41(3, 0); afB[1][1] = RDA41(3, 1);                                 \
    if (st) ST_B41(nboB, t + 1);                                                      \
    __builtin_amdgcn_s_setprio(1);                                                    \
    _Pragma("unroll")                                                                 \
    for (int kk = 0; kk < 2; ++kk)                                                    \
      _Pragma("unroll")                                                               \
      for (int m = 0; m < 2; ++m) {                                                   \
        acc[m + 2][0] = __builtin_amdgcn_mfma_f32_16x16x32_bf16(afB[m][kk], bfA[0][kk], acc[m + 2][0], 0, 0, 0); \
        acc[m + 2][1] = __builtin_amdgcn_mfma_f32_16x16x32_bf16(afB[m][kk], bfA[1][kk], acc[m + 2][1], 0, 0, 0); \
      }                                                                               \
    __builtin_amdgcn_s_setprio(0);                                                    \
    __builtin_amdgcn_s_barrier();                                                     \
    /* P3: MFMA m23 x n23 ; K-tile boundary drain */                                  \
    __builtin_amdgcn_s_setprio(1);                                                    \
    _Pragma("unroll")                                                                 \
    for (int kk = 0; kk < 2; ++kk)                                                    \
      _Pragma("unroll")                                                               \
      for (int m = 0; m < 2; ++m) {                                                   \
        acc[m + 2][2] = __builtin_amdgcn_mfma_f32_16x16x32_bf16(afB[m][kk], bfB[0][kk], acc[m + 2][2], 0, 0, 0); \
        acc[m + 2][3] = __builtin_amdgcn_mfma_f32_16x16x32_bf16(afB[m][kk], bfB[1][kk], acc[m + 2][3], 0, 0, 0); \
      }                                                                               \
    __builtin_amdgcn_s_setprio(0);                                                    \
    __builtin_amdgcn_sched_barrier(0);                                                \
    asm volatile("s_waitcnt vmcnt(0)" ::: "memory");                                  \
    __builtin_amdgcn_s_barrier();                                                     \
    __builtin_amdgcn_sched_barrier(0);                                                \
  }

// ---------------------------------------------------------------- fused QKV GEMM (256x128, 768 blocks)
__global__ __launch_bounds__(512, 2) void gemm_qkv8(
    const __bf16* __restrict__ Agp, const __bf16* __restrict__ Bgp,
    __bf16* __restrict__ qf, __bf16* __restrict__ kf, __bf16* __restrict__ vf) {
  __shared__ __bf16 LDSb[49152];
  const int tid = threadIdx.x;
  const int w = tid >> 6, l = tid & 63;
  const int wr = w >> 1, wc = w & 1;
  const int lr = l & 15, lg = l >> 4;
  int lin = blockIdx.y * 24 + blockIdx.x;          // 768 blocks; bijective XCD swizzle
  lin = (lin & 7) * 96 + (lin >> 3);
  const int bx = lin % 24, by = lin / 24;
  const int m0 = by * 256, n0 = bx * 128;
  const int srow = w * 16 + (l >> 3);
  const int sswz = ((l & 7) ^ ((l >> 3) & 7)) * 8;

  f32x4 acc[4][4] = {};
  bf16x8 afA[2][2], afB[2][2], bfA[2][2], bfB[2][2];

  GEMM8_KLOOP_41

  // epilogue: per-wave LDS re-stage (2 row-tiles x 2048) -> fragment order
  __bf16* wl = LDSb + w * 4096;
  const int colb = n0 + wc * 64;
  const int mat = colb >> 10;                 // 0=Q 1=K 2=V
  const int h = (colb >> 6) & 15;
  const int b = m0 >> 11;
  const float qsc = (mat == 0) ? 0.04508422f : 1.0f;  // C^-0.5 * log2(e)
#pragma unroll
  for (int mi = 0; mi < 4; ++mi) {
    const int rt = mi >> 1;
#pragma unroll
    for (int n = 0; n < 4; ++n) {
      const int d = n * 16 + lr;
#pragma unroll
      for (int j = 0; j < 4; ++j) {
        const int rowloc = (mi & 1) * 16 + lg * 4 + j;
        int off;
        if (mat < 2)
          off = ((d >> 4) & 3) * 512 + ((d >> 3) & 1) * 256 + rowloc * 8 + (d & 7);
        else
          off = (d >> 5) * 1024 + ((rowloc >> 4) & 1) * 512 + ((rowloc >> 3) & 1) * 256 +
                (d & 31) * 8 + (rowloc & 7);
        wl[rt * 2048 + off] = (__bf16)(acc[mi][n][j] * qsc);
      }
    }
  }
  __bf16* dstbase = (mat == 0 ? qf : mat == 1 ? kf : vf) + (size_t)(b * 16 + h) * BH_STRIDE_;
  const int rt0 = ((m0 + wr * 64) >> 5) & 63;
#pragma unroll
  for (int rt = 0; rt < 2; ++rt)
#pragma unroll
    for (int c = 0; c < 4; ++c) {
      const bf16x8 vchunk = *reinterpret_cast<const bf16x8*>(wl + rt * 2048 + c * 512 + l * 8);
      *reinterpret_cast<bf16x8*>(dstbase + (size_t)(rt0 + rt) * TILE_ELEMS_ + c * 512 + l * 8) = vchunk;
    }
}

// ---------------------------------------------------------------- proj GEMM (256x128, 256 blocks)
__global__ __launch_bounds__(512, 2) void gemm_proj8(
    const __bf16* __restrict__ Agp, const __bf16* __restrict__ Bgp,
    float* __restrict__ out, const float* __restrict__ bias) {
  __shared__ __bf16 LDSb[49152];
  const int tid = threadIdx.x;
  const int w = tid >> 6, l = tid & 63;
  const int wr = w >> 1, wc = w & 1;
  const int lr = l & 15, lg = l >> 4;
  int lin = blockIdx.y * 8 + blockIdx.x;           // 256 blocks; bijective XCD swizzle
  lin = (lin & 7) * 32 + (lin >> 3);
  const int bx = lin & 7, by = lin >> 3;
  const int m0 = by * 256, n0 = bx * 128;
  const int srow = w * 16 + (l >> 3);
  const int sswz = ((l & 7) ^ ((l >> 3) & 7)) * 8;

  f32x4 acc[4][4] = {};
  bf16x8 afA[2][2], afB[2][2], bfA[2][2], bfB[2][2];

  GEMM8_KLOOP_41

  // epilogue: direct f32 + bias store
  const int colb = n0 + wc * 64;
#pragma unroll
  for (int mi = 0; mi < 4; ++mi) {
    const int row = m0 + wr * 64 + mi * 16 + lg * 4;
#pragma unroll
    for (int n = 0; n < 4; ++n) {
      const int col = colb + n * 16 + lr;
      const float bv = bias[col];
#pragma unroll
      for (int j = 0; j < 4; ++j)
        out[(size_t)(row + j) * 1024 + col] = acc[mi][n][j] + bv;
    }
  }
}

// ---------------------------------------------------------------- helpers
__device__ __forceinline__ unsigned pk2(float a, float b) {
  const unsigned short ua = __builtin_bit_cast(unsigned short, (__bf16)a);
  const unsigned short ub = __builtin_bit_cast(unsigned short, (__bf16)b);
  return (unsigned)ua | ((unsigned)ub << 16);
}

// ---------------------------------------------------------------- flash attention v10 (R11-proven, unchanged)
#define LOADKV(SFX, TT)                                                          \
  do {                                                                           \
    const __bf16* kp_ = kfb + (size_t)(TT) * TILE_ELEMS_ + lx8;                  \
    k##SFX##0 = *reinterpret_cast<const bf16x8*>(kp_);                           \
    k##SFX##1 = *reinterpret_cast<const bf16x8*>(kp_ + 512);                     \
    k##SFX##2 = *reinterpret_cast<const bf16x8*>(kp_ + 1024);                    \
    k##SFX##3 = *reinterpret_cast<const bf16x8*>(kp_ + 1536);                    \
    const __bf16* vp_ = vfb + (size_t)(TT) * TILE_ELEMS_ + lx8;                  \
    v##SFX##0 = *reinterpret_cast<const bf16x8*>(vp_);                           \
    v##SFX##1 = *reinterpret_cast<const bf16x8*>(vp_ + 512);                     \
    v##SFX##2 = *reinterpret_cast<const bf16x8*>(vp_ + 1024);                    \
    v##SFX##3 = *reinterpret_cast<const bf16x8*>(vp_ + 1536);                    \
  } while (0)

#define TILE(SFX, MASKED)                                                        \
  do {                                                                           \
    f32x16 s = {};                                                               \
    __builtin_amdgcn_s_setprio(1);                                               \
    s = __builtin_amdgcn_mfma_f32_32x32x16_bf16(k##SFX##0, qf[0], s, 0, 0, 0);   \
    s = __builtin_amdgcn_mfma_f32_32x32x16_bf16(k##SFX##1, qf[1], s, 0, 0, 0);   \
    s = __builtin_amdgcn_mfma_f32_32x32x16_bf16(k##SFX##2, qf[2], s, 0, 0, 0);   \
    s = __builtin_amdgcn_mfma_f32_32x32x16_bf16(k##SFX##3, qf[3], s, 0, 0, 0);   \
    __builtin_amdgcn_s_setprio(0);                                               \
    float sv[16];                                                                \
    _Pragma("unroll") for (int r = 0; r < 16; ++r) sv[r] = s[r];                 \
    if (MASKED) {                                                                \
      _Pragma("unroll") for (int r = 0; r < 16; ++r) {                           \
        const int kvloc = (r & 3) + 8 * (r >> 2) + 4 * hi;                       \
        sv[r] = (kvloc <= lane31) ? sv[r] : -1e30f;                              \
      }                                                                          \
    }                                                                            \
    _Pragma("unroll") for (int r = 0; r < 16; ++r) sv[r] = fexp2(sv[r]);         \
    unsigned pwv[8];                                                             \
    _Pragma("unroll") for (int ks = 0; ks < 2; ++ks) {                           \
      const unsigned X0 = pk2(sv[ks * 8 + 0], sv[ks * 8 + 1]);                   \
      const unsigned X1 = pk2(sv[ks * 8 + 2], sv[ks * 8 + 3]);                   \
      const unsigned Y0 = pk2(sv[ks * 8 + 4], sv[ks * 8 + 5]);                   \
      const unsigned Y1 = pk2(sv[ks * 8 + 6], sv[ks * 8 + 7]);                   \
      const unsigned sX0 = __shfl_xor(X0, 32);                                   \
      const unsigned sX1 = __shfl_xor(X1, 32);                                   \
      const unsigned sY0 = __shfl_xor(Y0, 32);                                   \
      const unsigned sY1 = __shfl_xor(Y1, 32);                                   \
      pwv[ks * 4 + 0] = hi ? sY0 : X0;                                           \
      pwv[ks * 4 + 1] = hi ? sY1 : X1;                                           \
      pwv[ks * 4 + 2] = hi ? Y0 : sX0;                                           \
      pwv[ks * 4 + 3] = hi ? Y1 : sX1;                                           \
    }                                                                            \
    const uint4v u0 = {pwv[0], pwv[1], pwv[2], pwv[3]};                          \
    const uint4v u1 = {pwv[4], pwv[5], pwv[6], pwv[7]};                          \
    const bf16x8 pf0 = __builtin_bit_cast(bf16x8, u0);                           \
    const bf16x8 pf1 = __builtin_bit_cast(bf16x8, u1);                           \
    __builtin_amdgcn_s_setprio(1);                                               \
    acc0 = __builtin_amdgcn_mfma_f32_32x32x16_bf16(v##SFX##0, pf0, acc0, 0, 0, 0); \
    acc0 = __builtin_amdgcn_mfma_f32_32x32x16_bf16(v##SFX##1, pf1, acc0, 0, 0, 0); \
    acc1 = __builtin_amdgcn_mfma_f32_32x32x16_bf16(v##SFX##2, pf0, acc1, 0, 0, 0); \
    acc1 = __builtin_amdgcn_mfma_f32_32x32x16_bf16(v##SFX##3, pf1, acc1, 0, 0, 0); \
    __builtin_amdgcn_s_setprio(0);                                               \
    float b8[8];                                                                 \
    _Pragma("unroll") for (int r = 0; r < 8; ++r) b8[r] = sv[2 * r] + sv[2 * r + 1]; \
    _Pragma("unroll") for (int r = 0; r < 4; ++r) b8[r] = b8[2 * r] + b8[2 * r + 1]; \
    l_run += (b8[0] + b8[1]) + (b8[2] + b8[3]);                                  \
  } while (0)

__global__ __launch_bounds__(512) void attn_fwd(const __bf16* __restrict__ qfr,
                                                const __bf16* __restrict__ kfr,
                                                const __bf16* __restrict__ vfr,
                                                __bf16* __restrict__ ao) {
  __shared__ float Pls[4 * 64 * 34];
  const int tid = threadIdx.x;
  const int w = tid >> 6, l = tid & 63;
  const int p = w >> 1, hf = w & 1;
  const int lane31 = l & 31, hi = l >> 5;
  const int bh = blockIdx.x & 63;   // XCD affinity: lin%8 == bh%8
  const int qi = blockIdx.x >> 6;   // 0..7
  const int b = bh >> 4;
  const int qx = qi * 4 + p;        // 0..31; paired with 63-qx
  const size_t rowbase = (size_t)b * T_;
  const int hoff = (bh & 15) * D_;
  const int lx8 = l * 8;
  const __bf16* qfb = qfr + (size_t)bh * BH_STRIDE_;
  const __bf16* kfb = kfr + (size_t)bh * BH_STRIDE_;
  const __bf16* vfb = vfr + (size_t)bh * BH_STRIDE_;
  float* pb = Pls + p * (64 * 34) + l * 34;

  for (int phase = 0; phase < 2; ++phase) {
    const int qg = (phase ? 63 - qx : qx) * 32;
    const int ntiles = (qg >> 5) + 1;
    const int nh = ntiles >> 1;
    const int tb = hf ? nh : 0;
    const int te = hf ? ntiles : nh;
    const int nt = te - tb;
    const bool dm = (hf == 1);

    bf16x8 qf[4];
    {
      const __bf16* qp = qfb + (size_t)(qg >> 5) * TILE_ELEMS_ + lx8;
#pragma unroll
      for (int t4 = 0; t4 < 4; ++t4) qf[t4] = *reinterpret_cast<const bf16x8*>(qp + t4 * 512);
    }

    f32x16 acc0 = {};
    f32x16 acc1 = {};
    float l_run = 0.f;

    bf16x8 kA0, kA1, kA2, kA3, vA0, vA1, vA2, vA3;
    bf16x8 kB0, kB1, kB2, kB3, vB0, vB1, vB2, vB3;

    if (nt > 0) {
      LOADKV(A, tb);
      int i = 0;
      for (; i + 1 < nt; ++i) {
        if ((i & 1) == 0) { LOADKV(B, tb + i + 1); TILE(A, false); }
        else              { LOADKV(A, tb + i + 1); TILE(B, false); }
      }
      if ((i & 1) == 0) TILE(A, dm);
      else              TILE(B, dm);
    }

    if (hf) {
#pragma unroll
      for (int r = 0; r < 16; ++r) { pb[r] = acc0[r]; pb[16 + r] = acc1[r]; }
      pb[32] = l_run;
    }
    __syncthreads();
    if (!hf) {
#pragma unroll
      for (int r = 0; r < 16; ++r) { acc0[r] += pb[r]; acc1[r] += pb[16 + r]; }
      l_run += pb[32];
      l_run += __shfl_xor(l_run, 32);
      const float rl = 1.0f / l_run;
      __bf16* op = ao + (rowbase + qg + lane31) * C_ + hoff + hi * 4;
#pragma unroll
      for (int dblk = 0; dblk < 2; ++dblk)
#pragma unroll
        for (int qd = 0; qd < 4; ++qd) {
          bf16x4 ov;
#pragma unroll
          for (int j = 0; j < 4; ++j) {
            const float av = (dblk == 0) ? acc0[qd * 4 + j] : acc1[qd * 4 + j];
            ov[j] = (__bf16)(av * rl);
          }
          *reinterpret_cast<bf16x4*>(op + dblk * 32 + qd * 8) = ov;
        }
    }
    __syncthreads();
  }
}

// ---------------------------------------------------------------- launch
extern "C" void kernel_launch(void* const* d_in, const int* in_sizes, int n_in,
                              void* d_out, int out_size, void* d_ws, size_t ws_size,
                              hipStream_t stream) {
  const float* x  = (const float*)d_in[0];
  const float* Wq = (const float*)d_in[1];
  const float* Wk = (const float*)d_in[2];
  const float* Wv = (const float*)d_in[3];
  const float* Wp = (const float*)d_in[4];
  const float* bp = (const float*)d_in[5];
  float* out = (float*)d_out;

  const int NX = B_ * T_ * C_;
  const int NW = C_ * C_;

  __bf16* xb  = (__bf16*)d_ws;
  __bf16* wqb = xb + NX;     // wq|wk|wv contiguous => fused Bt [3072][1024]
  __bf16* wkb = wqb + NW;
  __bf16* wvb = wkb + NW;
  __bf16* wpb = wvb + NW;
  __bf16* qf  = wpb + NW;
  __bf16* kf  = qf + NX;
  __bf16* vf  = kf + NX;
  __bf16* aob = xb;          // xb dead after gemm_qkv8

  castall<<<12288, 256, 0, stream>>>(x, Wq, Wk, Wv, Wp, xb, wqb, wkb, wvb, wpb);

  gemm_qkv8<<<dim3(24, 32), 512, 0, stream>>>(xb, wqb, qf, kf, vf);
  attn_fwd<<<512, 512, 0, stream>>>(qf, kf, vf, aob);
  gemm_proj8<<<dim3(8, 32), 512, 0, stream>>>(aob, wpb, out, bp);
}

// Round 14
// 157.409 us; speedup vs baseline: 1.1529x; 1.0210x over previous
//
#include <hip/hip_runtime.h>
#include <cstdint>
#include <cstddef>

typedef __attribute__((ext_vector_type(8))) __bf16 bf16x8;
typedef __attribute__((ext_vector_type(4))) __bf16 bf16x4;
typedef __attribute__((ext_vector_type(4))) float f32x4;
typedef __attribute__((ext_vector_type(16))) float f32x16;
typedef __attribute__((ext_vector_type(4))) unsigned uint4v;

#define B_ 4
#define T_ 2048
#define C_ 1024
#define H_ 16
#define D_ 64
#define NTILES_ (T_ / 32)
#define TILE_ELEMS_ 2048
#define BH_STRIDE_ ((size_t)NTILES_ * TILE_ELEMS_)  // 131072

__device__ __forceinline__ float fexp2(float x) {
#if __has_builtin(__builtin_amdgcn_exp2f)
  return __builtin_amdgcn_exp2f(x);
#else
  return __expf(x * 0.69314718f);
#endif
}

// ---------------------------------------------------------------- fused cast f32->bf16
__global__ __launch_bounds__(256) void castall(
    const float* __restrict__ x, const float* __restrict__ wq, const float* __restrict__ wk,
    const float* __restrict__ wv, const float* __restrict__ wp,
    __bf16* __restrict__ xb, __bf16* __restrict__ wqb, __bf16* __restrict__ wkb,
    __bf16* __restrict__ wvb, __bf16* __restrict__ wpb) {
  const int bid = blockIdx.x;
  const float* src;
  __bf16* dst;
  if (bid < 8192)       { src = x  + (size_t)bid * 1024;           dst = xb  + (size_t)bid * 1024; }
  else if (bid < 9216)  { src = wq + (size_t)(bid - 8192) * 1024;  dst = wqb + (size_t)(bid - 8192) * 1024; }
  else if (bid < 10240) { src = wk + (size_t)(bid - 9216) * 1024;  dst = wkb + (size_t)(bid - 9216) * 1024; }
  else if (bid < 11264) { src = wv + (size_t)(bid - 10240) * 1024; dst = wvb + (size_t)(bid - 10240) * 1024; }
  else                  { src = wp + (size_t)(bid - 11264) * 1024; dst = wpb + (size_t)(bid - 11264) * 1024; }
  const int i = threadIdx.x * 4;
  float4 f = *reinterpret_cast<const float4*>(src + i);
  bf16x4 o;
  o[0] = (__bf16)f.x; o[1] = (__bf16)f.y; o[2] = (__bf16)f.z; o[3] = (__bf16)f.w;
  *reinterpret_cast<bf16x4*>(dst + i) = o;
}

// ---------------------------------------------------------------- async global->LDS
__device__ __forceinline__ void gload_lds16(const __bf16* g, __bf16* lds) {
  __builtin_amdgcn_global_load_lds(
      (const __attribute__((address_space(1))) void*)g,
      (__attribute__((address_space(3))) void*)lds, 16, 0, 0);
}

// ---------------------------------------------------------------- 8-phase GEMM, BM=256 x BN=128 (R12-proven)
#define ST_A41(BUFO, KT, HH)                                                          \
  do {                                                                                \
    const __bf16* s0_ = Agp + (size_t)(m0 + (HH) * 128 + srow) * 1024 + (KT) * 64 + sswz; \
    gload_lds16(s0_, LDSb + (BUFO) + (HH) * 8192 + w * 1024);                         \
    gload_lds16(s0_ + 8 * 1024, LDSb + (BUFO) + (HH) * 8192 + w * 1024 + 512);        \
  } while (0)
#define ST_B41(BUFO, KT)                                                              \
  do {                                                                                \
    const __bf16* s0_ = Bgp + (size_t)(n0 + srow) * 1024 + (KT) * 64 + sswz;          \
    gload_lds16(s0_, LDSb + 32768 + (BUFO) + w * 1024);                               \
    gload_lds16(s0_ + 8 * 1024, LDSb + 32768 + (BUFO) + w * 1024 + 512);              \
  } while (0)
#define RDA41(M, KK) (*reinterpret_cast<const bf16x8*>(                               \
    LDSb + bufoA + (wr * 64 + (M) * 16 + lr) * 64 + (((KK) * 32 + lg * 8) ^ ((lr & 7) * 8))))
#define RDB41(N, KK) (*reinterpret_cast<const bf16x8*>(                               \
    LDSb + 32768 + bufoB + (wc * 64 + (N) * 16 + lr) * 64 + (((KK) * 32 + lg * 8) ^ ((lr & 7) * 8))))

#define GEMM8_KLOOP_41                                                                \
  ST_A41(0, 0, 0); ST_A41(0, 0, 1); ST_B41(0, 0);                                     \
  __builtin_amdgcn_sched_barrier(0);                                                  \
  asm volatile("s_waitcnt vmcnt(0)" ::: "memory");                                    \
  __builtin_amdgcn_s_barrier();                                                       \
  __builtin_amdgcn_sched_barrier(0);                                                  \
  for (int t = 0; t < 16; ++t) {                                                      \
    const int bufoA = (t & 1) * 16384;                                                \
    const int bufoB = (t & 1) * 8192;                                                 \
    const int nboA = ((t + 1) & 1) * 16384;                                           \
    const int nboB = ((t + 1) & 1) * 8192;                                            \
    const bool st = t < 15;                                                           \
    afA[0][0] = RDA41(0, 0); afA[0][1] = RDA41(0, 1);                                 \
    afA[1][0] = RDA41(1, 0); afA[1][1] = RDA41(1, 1);                                 \
    bfA[0][0] = RDB41(0, 0); bfA[0][1] = RDB41(0, 1);                                 \
    bfA[1][0] = RDB41(1, 0); bfA[1][1] = RDB41(1, 1);                                 \
    if (st) ST_A41(nboA, t + 1, 0);                                                   \
    __builtin_amdgcn_s_setprio(1);                                                    \
    _Pragma("unroll")                                                                 \
    for (int kk = 0; kk < 2; ++kk)                                                    \
      _Pragma("unroll")                                                               \
      for (int m = 0; m < 2; ++m) {                                                   \
        acc[m][0] = __builtin_amdgcn_mfma_f32_16x16x32_bf16(afA[m][kk], bfA[0][kk], acc[m][0], 0, 0, 0); \
        acc[m][1] = __builtin_amdgcn_mfma_f32_16x16x32_bf16(afA[m][kk], bfA[1][kk], acc[m][1], 0, 0, 0); \
      }                                                                               \
    __builtin_amdgcn_s_setprio(0);                                                    \
    __builtin_amdgcn_s_barrier();                                                     \
    bfB[0][0] = RDB41(2, 0); bfB[0][1] = RDB41(2, 1);                                 \
    bfB[1][0] = RDB41(3, 0); bfB[1][1] = RDB41(3, 1);                                 \
    if (st) ST_A41(nboA, t + 1, 1);                                                   \
    __builtin_amdgcn_s_setprio(1);                                                    \
    _Pragma("unroll")                                                                 \
    for (int kk = 0; kk < 2; ++kk)                                                    \
      _Pragma("unroll")                                                               \
      for (int m = 0; m < 2; ++m) {                                                   \
        acc[m][2] = __builtin_amdgcn_mfma_f32_16x16x32_bf16(afA[m][kk], bfB[0][kk], acc[m][2], 0, 0, 0); \
        acc[m][3] = __builtin_amdgcn_mfma_f32_16x16x32_bf16(afA[m][kk], bfB[1][kk], acc[m][3], 0, 0, 0); \
      }                                                                               \
    __builtin_amdgcn_s_setprio(0);                                                    \
    __builtin_amdgcn_s_barrier();                                                     \
    afB[0][0] = RDA41(2, 0); afB[0][1] = RDA41(2, 1);                                 \
    afB[1][0] = RDA41(3, 0); afB[1][1] = RDA41(3, 1);                                 \
    if (st) ST_B41(nboB, t + 1);                                                      \
    __builtin_amdgcn_s_setprio(1);                                                    \
    _Pragma("unroll")                                                                 \
    for (int kk = 0; kk < 2; ++kk)                                                    \
      _Pragma("unroll")                                                               \
      for (int m = 0; m < 2; ++m) {                                                   \
        acc[m + 2][0] = __builtin_amdgcn_mfma_f32_16x16x32_bf16(afB[m][kk], bfA[0][kk], acc[m + 2][0], 0, 0, 0); \
        acc[m + 2][1] = __builtin_amdgcn_mfma_f32_16x16x32_bf16(afB[m][kk], bfA[1][kk], acc[m + 2][1], 0, 0, 0); \
      }                                                                               \
    __builtin_amdgcn_s_setprio(0);                                                    \
    __builtin_amdgcn_s_barrier();                                                     \
    __builtin_amdgcn_s_setprio(1);                                                    \
    _Pragma("unroll")                                                                 \
    for (int kk = 0; kk < 2; ++kk)                                                    \
      _Pragma("unroll")                                                               \
      for (int m = 0; m < 2; ++m) {                                                   \
        acc[m + 2][2] = __builtin_amdgcn_mfma_f32_16x16x32_bf16(afB[m][kk], bfB[0][kk], acc[m + 2][2], 0, 0, 0); \
        acc[m + 2][3] = __builtin_amdgcn_mfma_f32_16x16x32_bf16(afB[m][kk], bfB[1][kk], acc[m + 2][3], 0, 0, 0); \
      }                                                                               \
    __builtin_amdgcn_s_setprio(0);                                                    \
    __builtin_amdgcn_sched_barrier(0);                                                \
    asm volatile("s_waitcnt vmcnt(0)" ::: "memory");                                  \
    __builtin_amdgcn_s_barrier();                                                     \
    __builtin_amdgcn_sched_barrier(0);                                                \
  }

// ---------------------------------------------------------------- fused QKV GEMM (256x128, 768 blocks)
__global__ __launch_bounds__(512, 2) void gemm_qkv8(
    const __bf16* __restrict__ Agp, const __bf16* __restrict__ Bgp,
    __bf16* __restrict__ qf, __bf16* __restrict__ kf, __bf16* __restrict__ vf) {
  __shared__ __bf16 LDSb[49152];
  const int tid = threadIdx.x;
  const int w = tid >> 6, l = tid & 63;
  const int wr = w >> 1, wc = w & 1;
  const int lr = l & 15, lg = l >> 4;
  int lin = blockIdx.y * 24 + blockIdx.x;
  lin = (lin & 7) * 96 + (lin >> 3);
  const int bx = lin % 24, by = lin / 24;
  const int m0 = by * 256, n0 = bx * 128;
  const int srow = w * 16 + (l >> 3);
  const int sswz = ((l & 7) ^ ((l >> 3) & 7)) * 8;

  f32x4 acc[4][4] = {};
  bf16x8 afA[2][2], afB[2][2], bfA[2][2], bfB[2][2];

  GEMM8_KLOOP_41

  __bf16* wl = LDSb + w * 4096;
  const int colb = n0 + wc * 64;
  const int mat = colb >> 10;
  const int h = (colb >> 6) & 15;
  const int b = m0 >> 11;
  const float qsc = (mat == 0) ? 0.04508422f : 1.0f;  // C^-0.5 * log2(e)
#pragma unroll
  for (int mi = 0; mi < 4; ++mi) {
    const int rt = mi >> 1;
#pragma unroll
    for (int n = 0; n < 4; ++n) {
      const int d = n * 16 + lr;
#pragma unroll
      for (int j = 0; j < 4; ++j) {
        const int rowloc = (mi & 1) * 16 + lg * 4 + j;
        int off;
        if (mat < 2)
          off = ((d >> 4) & 3) * 512 + ((d >> 3) & 1) * 256 + rowloc * 8 + (d & 7);
        else
          off = (d >> 5) * 1024 + ((rowloc >> 4) & 1) * 512 + ((rowloc >> 3) & 1) * 256 +
                (d & 31) * 8 + (rowloc & 7);
        wl[rt * 2048 + off] = (__bf16)(acc[mi][n][j] * qsc);
      }
    }
  }
  __bf16* dstbase = (mat == 0 ? qf : mat == 1 ? kf : vf) + (size_t)(b * 16 + h) * BH_STRIDE_;
  const int rt0 = ((m0 + wr * 64) >> 5) & 63;
#pragma unroll
  for (int rt = 0; rt < 2; ++rt)
#pragma unroll
    for (int c = 0; c < 4; ++c) {
      const bf16x8 vchunk = *reinterpret_cast<const bf16x8*>(wl + rt * 2048 + c * 512 + l * 8);
      *reinterpret_cast<bf16x8*>(dstbase + (size_t)(rt0 + rt) * TILE_ELEMS_ + c * 512 + l * 8) = vchunk;
    }
}

// ---------------------------------------------------------------- proj GEMM (256x128, 256 blocks)
__global__ __launch_bounds__(512, 2) void gemm_proj8(
    const __bf16* __restrict__ Agp, const __bf16* __restrict__ Bgp,
    float* __restrict__ out, const float* __restrict__ bias) {
  __shared__ __bf16 LDSb[49152];
  const int tid = threadIdx.x;
  const int w = tid >> 6, l = tid & 63;
  const int wr = w >> 1, wc = w & 1;
  const int lr = l & 15, lg = l >> 4;
  int lin = blockIdx.y * 8 + blockIdx.x;
  lin = (lin & 7) * 32 + (lin >> 3);
  const int bx = lin & 7, by = lin >> 3;
  const int m0 = by * 256, n0 = bx * 128;
  const int srow = w * 16 + (l >> 3);
  const int sswz = ((l & 7) ^ ((l >> 3) & 7)) * 8;

  f32x4 acc[4][4] = {};
  bf16x8 afA[2][2], afB[2][2], bfA[2][2], bfB[2][2];

  GEMM8_KLOOP_41

  const int colb = n0 + wc * 64;
#pragma unroll
  for (int mi = 0; mi < 4; ++mi) {
    const int row = m0 + wr * 64 + mi * 16 + lg * 4;
#pragma unroll
    for (int n = 0; n < 4; ++n) {
      const int col = colb + n * 16 + lr;
      const float bv = bias[col];
#pragma unroll
      for (int j = 0; j < 4; ++j)
        out[(size_t)(row + j) * 1024 + col] = acc[mi][n][j] + bv;
    }
  }
}

// ---------------------------------------------------------------- helpers
__device__ __forceinline__ unsigned pk2(float a, float b) {
  const unsigned short ua = __builtin_bit_cast(unsigned short, (__bf16)a);
  const unsigned short ub = __builtin_bit_cast(unsigned short, (__bf16)b);
  return (unsigned)ua | ((unsigned)ub << 16);
}

// P^T word exchange. Need: w0 = {lo-lanes: X, hi-lanes: partner's Y},
// w2 = {lo-lanes: partner's X, hi-lanes: Y}.
// permlane32_swap(vdst=X, vsrc=Y) exchanges X.row1 <-> Y.row0:
//   newX = {X.lo, Y.lo} = w0 ; newY = {X.hi, Y.hi} = w2.  (ISA: DATA0 row1 <-> DATA1 row0)
// Fallback: R12-proven shfl path.
__device__ __forceinline__ void exch2(unsigned X, unsigned Y, int hi,
                                      unsigned& w0, unsigned& w2) {
#if __has_builtin(__builtin_amdgcn_permlane32_swap)
  auto r = __builtin_amdgcn_permlane32_swap(X, Y, false, false);
  w0 = r[0];
  w2 = r[1];
#else
  const unsigned sX = __shfl_xor(X, 32);
  const unsigned sY = __shfl_xor(Y, 32);
  w0 = hi ? sY : X;
  w2 = hi ? Y : sX;
#endif
}

// ---------------------------------------------------------------- flash attention v12
// = v10 structure (R11/R12-proven), no setprio, P^T exchange via exch2
// (permlane32_swap when available, shfl fallback).
#define LOADKV(SFX, TT)                                                          \
  do {                                                                           \
    const __bf16* kp_ = kfb + (size_t)(TT) * TILE_ELEMS_ + lx8;                  \
    k##SFX##0 = *reinterpret_cast<const bf16x8*>(kp_);                           \
    k##SFX##1 = *reinterpret_cast<const bf16x8*>(kp_ + 512);                     \
    k##SFX##2 = *reinterpret_cast<const bf16x8*>(kp_ + 1024);                    \
    k##SFX##3 = *reinterpret_cast<const bf16x8*>(kp_ + 1536);                    \
    const __bf16* vp_ = vfb + (size_t)(TT) * TILE_ELEMS_ + lx8;                  \
    v##SFX##0 = *reinterpret_cast<const bf16x8*>(vp_);                           \
    v##SFX##1 = *reinterpret_cast<const bf16x8*>(vp_ + 512);                     \
    v##SFX##2 = *reinterpret_cast<const bf16x8*>(vp_ + 1024);                    \
    v##SFX##3 = *reinterpret_cast<const bf16x8*>(vp_ + 1536);                    \
  } while (0)

#define TILE(SFX, MASKED)                                                        \
  do {                                                                           \
    f32x16 s = {};                                                               \
    s = __builtin_amdgcn_mfma_f32_32x32x16_bf16(k##SFX##0, qf[0], s, 0, 0, 0);   \
    s = __builtin_amdgcn_mfma_f32_32x32x16_bf16(k##SFX##1, qf[1], s, 0, 0, 0);   \
    s = __builtin_amdgcn_mfma_f32_32x32x16_bf16(k##SFX##2, qf[2], s, 0, 0, 0);   \
    s = __builtin_amdgcn_mfma_f32_32x32x16_bf16(k##SFX##3, qf[3], s, 0, 0, 0);   \
    float sv[16];                                                                \
    _Pragma("unroll") for (int r = 0; r < 16; ++r) sv[r] = s[r];                 \
    if (MASKED) {                                                                \
      _Pragma("unroll") for (int r = 0; r < 16; ++r) {                           \
        const int kvloc = (r & 3) + 8 * (r >> 2) + 4 * hi;                       \
        sv[r] = (kvloc <= lane31) ? sv[r] : -1e30f;                              \
      }                                                                          \
    }                                                                            \
    _Pragma("unroll") for (int r = 0; r < 16; ++r) sv[r] = fexp2(sv[r]);         \
    unsigned pwv[8];                                                             \
    _Pragma("unroll") for (int ks = 0; ks < 2; ++ks) {                           \
      const unsigned X0 = pk2(sv[ks * 8 + 0], sv[ks * 8 + 1]);                   \
      const unsigned X1 = pk2(sv[ks * 8 + 2], sv[ks * 8 + 3]);                   \
      const unsigned Y0 = pk2(sv[ks * 8 + 4], sv[ks * 8 + 5]);                   \
      const unsigned Y1 = pk2(sv[ks * 8 + 6], sv[ks * 8 + 7]);                   \
      exch2(X0, Y0, hi, pwv[ks * 4 + 0], pwv[ks * 4 + 2]);                       \
      exch2(X1, Y1, hi, pwv[ks * 4 + 1], pwv[ks * 4 + 3]);                       \
    }                                                                            \
    const uint4v u0 = {pwv[0], pwv[1], pwv[2], pwv[3]};                          \
    const uint4v u1 = {pwv[4], pwv[5], pwv[6], pwv[7]};                          \
    const bf16x8 pf0 = __builtin_bit_cast(bf16x8, u0);                           \
    const bf16x8 pf1 = __builtin_bit_cast(bf16x8, u1);                           \
    acc0 = __builtin_amdgcn_mfma_f32_32x32x16_bf16(v##SFX##0, pf0, acc0, 0, 0, 0); \
    acc0 = __builtin_amdgcn_mfma_f32_32x32x16_bf16(v##SFX##1, pf1, acc0, 0, 0, 0); \
    acc1 = __builtin_amdgcn_mfma_f32_32x32x16_bf16(v##SFX##2, pf0, acc1, 0, 0, 0); \
    acc1 = __builtin_amdgcn_mfma_f32_32x32x16_bf16(v##SFX##3, pf1, acc1, 0, 0, 0); \
    float b8[8];                                                                 \
    _Pragma("unroll") for (int r = 0; r < 8; ++r) b8[r] = sv[2 * r] + sv[2 * r + 1]; \
    _Pragma("unroll") for (int r = 0; r < 4; ++r) b8[r] = b8[2 * r] + b8[2 * r + 1]; \
    l_run += (b8[0] + b8[1]) + (b8[2] + b8[3]);                                  \
  } while (0)

__global__ __launch_bounds__(512) void attn_fwd(const __bf16* __restrict__ qfr,
                                                const __bf16* __restrict__ kfr,
                                                const __bf16* __restrict__ vfr,
                                                __bf16* __restrict__ ao) {
  __shared__ float Pls[4 * 64 * 34];
  const int tid = threadIdx.x;
  const int w = tid >> 6, l = tid & 63;
  const int p = w >> 1, hf = w & 1;
  const int lane31 = l & 31, hi = l >> 5;
  const int bh = blockIdx.x & 63;   // XCD affinity: lin%8 == bh%8
  const int qi = blockIdx.x >> 6;   // 0..7
  const int b = bh >> 4;
  const int qx = qi * 4 + p;        // 0..31; paired with 63-qx
  const size_t rowbase = (size_t)b * T_;
  const int hoff = (bh & 15) * D_;
  const int lx8 = l * 8;
  const __bf16* qfb = qfr + (size_t)bh * BH_STRIDE_;
  const __bf16* kfb = kfr + (size_t)bh * BH_STRIDE_;
  const __bf16* vfb = vfr + (size_t)bh * BH_STRIDE_;
  float* pb = Pls + p * (64 * 34) + l * 34;

  for (int phase = 0; phase < 2; ++phase) {
    const int qg = (phase ? 63 - qx : qx) * 32;
    const int ntiles = (qg >> 5) + 1;
    const int nh = ntiles >> 1;
    const int tb = hf ? nh : 0;
    const int te = hf ? ntiles : nh;
    const int nt = te - tb;
    const bool dm = (hf == 1);

    bf16x8 qf[4];
    {
      const __bf16* qp = qfb + (size_t)(qg >> 5) * TILE_ELEMS_ + lx8;
#pragma unroll
      for (int t4 = 0; t4 < 4; ++t4) qf[t4] = *reinterpret_cast<const bf16x8*>(qp + t4 * 512);
    }

    f32x16 acc0 = {};
    f32x16 acc1 = {};
    float l_run = 0.f;

    bf16x8 kA0, kA1, kA2, kA3, vA0, vA1, vA2, vA3;
    bf16x8 kB0, kB1, kB2, kB3, vB0, vB1, vB2, vB3;

    if (nt > 0) {
      LOADKV(A, tb);
      int i = 0;
      for (; i + 1 < nt; ++i) {
        if ((i & 1) == 0) { LOADKV(B, tb + i + 1); TILE(A, false); }
        else              { LOADKV(A, tb + i + 1); TILE(B, false); }
      }
      if ((i & 1) == 0) TILE(A, dm);
      else              TILE(B, dm);
    }

    if (hf) {
#pragma unroll
      for (int r = 0; r < 16; ++r) { pb[r] = acc0[r]; pb[16 + r] = acc1[r]; }
      pb[32] = l_run;
    }
    __syncthreads();
    if (!hf) {
#pragma unroll
      for (int r = 0; r < 16; ++r) { acc0[r] += pb[r]; acc1[r] += pb[16 + r]; }
      l_run += pb[32];
      l_run += __shfl_xor(l_run, 32);
      const float rl = 1.0f / l_run;
      __bf16* op = ao + (rowbase + qg + lane31) * C_ + hoff + hi * 4;
#pragma unroll
      for (int dblk = 0; dblk < 2; ++dblk)
#pragma unroll
        for (int qd = 0; qd < 4; ++qd) {
          bf16x4 ov;
#pragma unroll
          for (int j = 0; j < 4; ++j) {
            const float av = (dblk == 0) ? acc0[qd * 4 + j] : acc1[qd * 4 + j];
            ov[j] = (__bf16)(av * rl);
          }
          *reinterpret_cast<bf16x4*>(op + dblk * 32 + qd * 8) = ov;
        }
    }
    __syncthreads();
  }
}

// ---------------------------------------------------------------- launch
extern "C" void kernel_launch(void* const* d_in, const int* in_sizes, int n_in,
                              void* d_out, int out_size, void* d_ws, size_t ws_size,
                              hipStream_t stream) {
  const float* x  = (const float*)d_in[0];
  const float* Wq = (const float*)d_in[1];
  const float* Wk = (const float*)d_in[2];
  const float* Wv = (const float*)d_in[3];
  const float* Wp = (const float*)d_in[4];
  const float* bp = (const float*)d_in[5];
  float* out = (float*)d_out;

  const int NX = B_ * T_ * C_;
  const int NW = C_ * C_;

  __bf16* xb  = (__bf16*)d_ws;
  __bf16* wqb = xb + NX;
  __bf16* wkb = wqb + NW;
  __bf16* wvb = wkb + NW;
  __bf16* wpb = wvb + NW;
  __bf16* qf  = wpb + NW;
  __bf16* kf  = qf + NX;
  __bf16* vf  = kf + NX;
  __bf16* aob = xb;  // xb dead after gemm_qkv8

  castall<<<12288, 256, 0, stream>>>(x, Wq, Wk, Wv, Wp, xb, wqb, wkb, wvb, wpb);

  gemm_qkv8<<<dim3(24, 32), 512, 0, stream>>>(xb, wqb, qf, kf, vf);
  attn_fwd<<<512, 512, 0, stream>>>(qf, kf, vf, aob);
  gemm_proj8<<<dim3(8, 32), 512, 0, stream>>>(aob, wpb, out, bp);
}